// Round 1
// baseline (197.847 us; speedup 1.0000x reference)
//
#include <hip/hip_runtime.h>
#include <hip/hip_bf16.h>

// Problem constants: B=4, T=4096, C=1024, H=16, D=64
#define BB 4
#define TT 4096
#define CC 1024
#define HH 16
#define DD 64

typedef __attribute__((ext_vector_type(8))) short short8;
typedef __attribute__((ext_vector_type(8))) __bf16 bf16x8;
typedef __attribute__((ext_vector_type(4))) float f32x4;

static __device__ __forceinline__ unsigned short f2bf(float f) {
    unsigned int u = __builtin_bit_cast(unsigned int, f);
    unsigned int r = (u + 0x7FFFu + ((u >> 16) & 1u)) >> 16;
    return (unsigned short)r;
}

// ---------------- fp32 -> bf16 conversion (vectorized) ----------------
__global__ void k_f32_to_bf16(const float* __restrict__ src,
                              unsigned short* __restrict__ dst, int n4) {
    int i = blockIdx.x * 256 + threadIdx.x;
    if (i >= n4) return;
    float4 v = ((const float4*)src)[i];
    ushort4 o;
    o.x = f2bf(v.x); o.y = f2bf(v.y); o.z = f2bf(v.z); o.w = f2bf(v.w);
    ((ushort4*)dst)[i] = o;
}

// ---------------- bf16 GEMM: C[m,n] = sum_k A[m,k]*B[n,k] + bias[n] ----------------
// A: M x K bf16 row-major; B: N x K bf16 row-major (i.e. X @ W^T form). C fp32.
// 128x128 tile, BK=32, 4 waves, each wave 64x64 (4x4 of 16x16x32 MFMA).
#define BM 128
#define BN 128
#define BK 32

__global__ __launch_bounds__(256, 2)
void k_gemm_bt_bias(const unsigned short* __restrict__ A,
                    const unsigned short* __restrict__ B,
                    const float* __restrict__ bias,
                    float* __restrict__ C,
                    int M, int N, int K)
{
    __shared__ unsigned short As[BM * BK]; // 8 KB
    __shared__ unsigned short Bs[BN * BK]; // 8 KB
    const int tid  = threadIdx.x;
    const int wave = tid >> 6;
    const int lane = tid & 63;
    const int bn = blockIdx.x, bm = blockIdx.y;
    const int wr = wave >> 1, wc = wave & 1;

    f32x4 acc[4][4] = {};

    const int lrow = lane >> 2;        // 0..15 (row within 16-row segment)
    const int lcol = (lane & 3) * 8;   // k element offset 0,8,16,24

    const unsigned short* Abase = A + (size_t)(bm * BM) * K;
    const unsigned short* Bbase = B + (size_t)(bn * BN) * K;

    const int kg = (lane >> 4) * 8;    // fragment k offset within BK
    const int fr = lane & 15;          // fragment row

    for (int k0 = 0; k0 < K; k0 += BK) {
        // stage A,B tiles: 8 KB each = 8 segments of 1024B; 2 per wave each
        #pragma unroll
        for (int i = 0; i < 2; ++i) {
            int s = wave * 2 + i;
            const unsigned short* ga = Abase + (size_t)(s * 16 + lrow) * K + (k0 + lcol);
            __builtin_amdgcn_global_load_lds(
                (const __attribute__((address_space(1))) void*)ga,
                (__attribute__((address_space(3))) void*)&As[s * 512], 16, 0, 0);
            const unsigned short* gb = Bbase + (size_t)(s * 16 + lrow) * K + (k0 + lcol);
            __builtin_amdgcn_global_load_lds(
                (const __attribute__((address_space(1))) void*)gb,
                (__attribute__((address_space(3))) void*)&Bs[s * 512], 16, 0, 0);
        }
        __syncthreads();  // drains vmcnt before barrier -> tiles visible

        short8 af[4], bfr[4];
        #pragma unroll
        for (int m = 0; m < 4; ++m) {
            int row = wr * 64 + m * 16 + fr;
            af[m] = *(const short8*)&As[row * BK + kg];
        }
        #pragma unroll
        for (int n = 0; n < 4; ++n) {
            int row = wc * 64 + n * 16 + fr;
            bfr[n] = *(const short8*)&Bs[row * BK + kg];
        }
        #pragma unroll
        for (int m = 0; m < 4; ++m)
            #pragma unroll
            for (int n = 0; n < 4; ++n)
                acc[m][n] = __builtin_amdgcn_mfma_f32_16x16x32_bf16(
                    __builtin_bit_cast(bf16x8, af[m]),
                    __builtin_bit_cast(bf16x8, bfr[n]),
                    acc[m][n], 0, 0, 0);
        __syncthreads();  // all waves done reading before next overwrite
    }

    // epilogue: C/D layout col=lane&15, row=(lane>>4)*4 + j (verified gfx950)
    const int cg = lane & 15;
    const int rg = (lane >> 4) * 4;
    #pragma unroll
    for (int m = 0; m < 4; ++m) {
        #pragma unroll
        for (int n = 0; n < 4; ++n) {
            int col = bn * BN + wc * 64 + n * 16 + cg;
            float bv = bias[col];
            #pragma unroll
            for (int j = 0; j < 4; ++j) {
                int row = bm * BM + wr * 64 + m * 16 + rg + j;
                C[(size_t)row * N + col] = acc[m][n][j] + bv;
            }
        }
    }
}

// ---------------- column sum of squares: S[b,c] = sum_t w[b,t,c]^2 ----------------
__global__ void k_colsum_sq(const float* __restrict__ w, float* __restrict__ S) {
    // grid: (C/256, T/256, B)
    int c  = blockIdx.x * 256 + threadIdx.x;
    int t0 = blockIdx.y * 256;
    int b  = blockIdx.z;
    const float* p = w + ((size_t)b * TT + t0) * CC + c;
    float s = 0.f;
    #pragma unroll 4
    for (int j = 0; j < 256; ++j) {
        float v = p[(size_t)j * CC];
        s += v * v;
    }
    atomicAdd(&S[b * CC + c], s);
}

// ---------------- per-row: tmp, head-softmax Pi, accumulate sumPi & dotsU ----------------
// One wave per token row (1024 f32, contiguous). 4 waves/block, 8 rows/wave.
__global__ __launch_bounds__(256)
void k_row_softmax(const float* __restrict__ w, const float* __restrict__ S,
                   const float* __restrict__ temp,
                   float* __restrict__ Pi, float* __restrict__ dotsU,
                   float* __restrict__ sumPi)
{
    __shared__ float dots_local[CC];
    __shared__ float sPi_local[HH];
    const int tid  = threadIdx.x;
    const int wave = tid >> 6;
    const int lane = tid & 63;
    const int b    = blockIdx.x >> 7;   // 128 blocks per batch
    const int tile = blockIdx.x & 127;

    for (int c = tid; c < CC; c += 256) dots_local[c] = 0.f;
    if (tid < HH) sPi_local[tid] = 0.f;
    __syncthreads();

    const int g  = lane >> 4;   // 16-lane group -> sub-head index
    const int li = lane & 15;

    // chunk q covers c = q*256 + lane*4 .. +3 ; head(q,g) = q*4+g
    float inv[4][4];
    float tsc[4];
    #pragma unroll
    for (int q = 0; q < 4; ++q) {
        int c = q * 256 + lane * 4;
        float4 sv = *(const float4*)&S[b * CC + c];
        inv[q][0] = 1.f / fmaxf(sv.x, 1e-24f);
        inv[q][1] = 1.f / fmaxf(sv.y, 1e-24f);
        inv[q][2] = 1.f / fmaxf(sv.z, 1e-24f);
        inv[q][3] = 1.f / fmaxf(sv.w, 1e-24f);
        tsc[q] = temp[q * 4 + g];
    }

    float dacc[4][4] = {};
    float sPiAcc[4] = {};

    for (int i = 0; i < 8; ++i) {
        int t = tile * 32 + wave * 8 + i;
        const float* row = w + ((size_t)b * TT + t) * CC;
        float4 wv[4];
        float pq[4];
        #pragma unroll
        for (int q = 0; q < 4; ++q) {
            wv[q] = *(const float4*)&row[q * 256 + lane * 4];
            pq[q] = wv[q].x * wv[q].x * inv[q][0] + wv[q].y * wv[q].y * inv[q][1]
                  + wv[q].z * wv[q].z * inv[q][2] + wv[q].w * wv[q].w * inv[q][3];
        }
        // reduce over the 16 lanes of each group -> per-head sum_d w_normed^2
        #pragma unroll
        for (int off = 1; off < 16; off <<= 1) {
            #pragma unroll
            for (int q = 0; q < 4; ++q) pq[q] += __shfl_xor(pq[q], off);
        }
        float mx = -1e30f;
        #pragma unroll
        for (int q = 0; q < 4; ++q) { pq[q] *= tsc[q]; mx = fmaxf(mx, pq[q]); }
        mx = fmaxf(mx, __shfl_xor(mx, 16));
        mx = fmaxf(mx, __shfl_xor(mx, 32));
        float e[4], ssum = 0.f;
        #pragma unroll
        for (int q = 0; q < 4; ++q) { e[q] = __expf(pq[q] - mx); ssum += e[q]; }
        ssum += __shfl_xor(ssum, 16);
        ssum += __shfl_xor(ssum, 32);
        float rs = 1.f / ssum;
        #pragma unroll
        for (int q = 0; q < 4; ++q) {
            float piq = e[q] * rs;
            dacc[q][0] += piq * wv[q].x * wv[q].x;
            dacc[q][1] += piq * wv[q].y * wv[q].y;
            dacc[q][2] += piq * wv[q].z * wv[q].z;
            dacc[q][3] += piq * wv[q].w * wv[q].w;
            if (li == 0) {
                Pi[((size_t)(b * HH + q * 4 + g)) * TT + t] = piq;
                sPiAcc[q] += piq;
            }
        }
    }

    #pragma unroll
    for (int q = 0; q < 4; ++q) {
        int c = q * 256 + lane * 4;
        atomicAdd(&dots_local[c + 0], dacc[q][0]);
        atomicAdd(&dots_local[c + 1], dacc[q][1]);
        atomicAdd(&dots_local[c + 2], dacc[q][2]);
        atomicAdd(&dots_local[c + 3], dacc[q][3]);
        if (li == 0) atomicAdd(&sPi_local[q * 4 + g], sPiAcc[q]);
    }
    __syncthreads();
    for (int c = tid; c < CC; c += 256) atomicAdd(&dotsU[b * CC + c], dots_local[c]);
    if (tid < HH) atomicAdd(&sumPi[b * HH + tid], sPi_local[tid]);
}

// ---------------- attnScale[b,c] = 1/(1 + dotsU/(sumPi+1e-8)) ----------------
__global__ void k_attnscale(const float* __restrict__ dotsU,
                            const float* __restrict__ sumPi,
                            float* __restrict__ attnScale) {
    int i = blockIdx.x * 256 + threadIdx.x;   // over B*C = 4096
    if (i >= BB * CC) return;
    int b = i >> 10;
    int h = (i >> 6) & 15;
    float sp = sumPi[b * HH + h] + 1e-8f;
    attnScale[i] = 1.f / (1.f + dotsU[i] / sp);
}

// ---------------- y[b,t,c] = bf16( -(w*Pi[b,h,t]) * attnScale[b,c] ) ----------------
__global__ void k_make_y(const float* __restrict__ w, const float* __restrict__ Pi,
                         const float* __restrict__ attnScale,
                         unsigned short* __restrict__ y)
{
    size_t i = (size_t)blockIdx.x * 256 + threadIdx.x;  // float4 chunk id
    size_t flat = i * 4;
    int c = (int)(flat & (CC - 1));
    size_t bt = flat >> 10;         // b*T + t
    int t = (int)(bt & (TT - 1));
    int b = (int)(bt >> 12);
    int h = c >> 6;
    float pi = Pi[((size_t)(b * HH + h)) * TT + t];
    float4 wv = *(const float4*)&w[flat];
    float4 av = *(const float4*)&attnScale[b * CC + c];
    ushort4 o;
    o.x = f2bf(-(wv.x * pi) * av.x);
    o.y = f2bf(-(wv.y * pi) * av.y);
    o.z = f2bf(-(wv.z * pi) * av.z);
    o.w = f2bf(-(wv.w * pi) * av.w);
    *(ushort4*)&y[flat] = o;
}

// ---------------- launch ----------------
extern "C" void kernel_launch(void* const* d_in, const int* in_sizes, int n_in,
                              void* d_out, int out_size, void* d_ws, size_t ws_size,
                              hipStream_t stream) {
    const float* x      = (const float*)d_in[0];
    const float* W_attn = (const float*)d_in[1];
    const float* b_attn = (const float*)d_in[2];
    const float* W_proj = (const float*)d_in[3];
    const float* b_proj = (const float*)d_in[4];
    const float* temp   = (const float*)d_in[5];
    // d_in[6] = n_head (16), hard-coded

    char* ws = (char*)d_ws;
    unsigned short* xy_bf16 = (unsigned short*)(ws);             // 33554432 B (x, later y)
    unsigned short* Wa_bf16 = (unsigned short*)(ws + 33554432);  // 2097152 B
    unsigned short* Wp_bf16 = (unsigned short*)(ws + 35651584);  // 2097152 B
    float* Pi        = (float*)(ws + 37748736);  // 1048576 B
    float* S         = (float*)(ws + 38797312);  // 16384 B
    float* dotsU     = (float*)(ws + 38813696);  // 16384 B
    float* sumPi     = (float*)(ws + 38830080);  // 256 B
    float* attnScale = (float*)(ws + 38830336);  // 16384 B
    float* wbuf = (float*)d_out;  // (B,T,C) fp32 intermediate lives in d_out

    // convert inputs to bf16
    k_f32_to_bf16<<<dim3(16384), dim3(256), 0, stream>>>(x, xy_bf16, 4194304);
    k_f32_to_bf16<<<dim3(1024), dim3(256), 0, stream>>>(W_attn, Wa_bf16, 262144);
    k_f32_to_bf16<<<dim3(1024), dim3(256), 0, stream>>>(W_proj, Wp_bf16, 262144);

    // zero accumulators (S, dotsU, sumPi are contiguous: 16384+16384+256)
    hipMemsetAsync(S, 0, 16384 + 16384 + 256, stream);

    // GEMM1: w = x @ W_attn^T + b_attn  -> d_out (fp32)
    k_gemm_bt_bias<<<dim3(8, 128), dim3(256), 0, stream>>>(
        xy_bf16, Wa_bf16, b_attn, wbuf, BB * TT, CC, CC);

    // S[b,c] = sum_t w^2
    k_colsum_sq<<<dim3(4, 16, 4), dim3(256), 0, stream>>>(wbuf, S);

    // per-row softmax over heads + accumulate sumPi, dotsU
    k_row_softmax<<<dim3(512), dim3(256), 0, stream>>>(wbuf, S, temp, Pi, dotsU, sumPi);

    // attn scale
    k_attnscale<<<dim3(16), dim3(256), 0, stream>>>(dotsU, sumPi, attnScale);

    // y (bf16) overwrites x_bf16 region
    k_make_y<<<dim3(16384), dim3(256), 0, stream>>>(wbuf, Pi, attnScale, xy_bf16);

    // GEMM2: out = y @ W_proj^T + b_proj -> d_out (fp32)
    k_gemm_bt_bias<<<dim3(8, 128), dim3(256), 0, stream>>>(
        xy_bf16, Wp_bf16, b_proj, (float*)d_out, BB * TT, CC, CC);
}

// Round 2
// 186.366 us; speedup vs baseline: 1.0616x; 1.0616x over previous
//
#include <hip/hip_runtime.h>
#include <hip/hip_bf16.h>

// Problem constants: B=4, T=4096, C=1024, H=16, D=64
#define BB 4
#define TT 4096
#define CC 1024
#define HH 16
#define DD 64

typedef __attribute__((ext_vector_type(8))) short short8;
typedef __attribute__((ext_vector_type(8))) __bf16 bf16x8;
typedef __attribute__((ext_vector_type(4))) float f32x4;

static __device__ __forceinline__ unsigned short f2bf(float f) {
    unsigned int u = __builtin_bit_cast(unsigned int, f);
    unsigned int r = (u + 0x7FFFu + ((u >> 16) & 1u)) >> 16;
    return (unsigned short)r;
}

// ---------------- fp32 -> bf16 conversion (vectorized) ----------------
__global__ void k_f32_to_bf16(const float* __restrict__ src,
                              unsigned short* __restrict__ dst, int n4) {
    int i = blockIdx.x * 256 + threadIdx.x;
    if (i >= n4) return;
    float4 v = ((const float4*)src)[i];
    ushort4 o;
    o.x = f2bf(v.x); o.y = f2bf(v.y); o.z = f2bf(v.z); o.w = f2bf(v.w);
    ((ushort4*)dst)[i] = o;
}

// ---------------- bf16 GEMM: C[m,n] = sum_k A[m,k]*B[n,k] + bias[n] ----------------
// A: M x K bf16 row-major; B: N x K bf16 row-major (X @ W^T form). C fp32.
// 128x128 tile, BK=32, 4 waves, each wave 64x64 (4x4 of 16x16x32 MFMA).
// 1D grid with XCD-aware bijective swizzle (gridDim.x % 8 == 0).
// ACCUM_S: additionally accumulate per-column sum of squares of (acc+bias) into S[b*C+col].
#define BM 128
#define BN 128
#define BK 32

template<int ACCUM_S>
__global__ __launch_bounds__(256)
void k_gemm_bt_bias(const unsigned short* __restrict__ A,
                    const unsigned short* __restrict__ B,
                    const float* __restrict__ bias,
                    float* __restrict__ C,
                    float* __restrict__ S,
                    int M, int N, int K)
{
    __shared__ unsigned short As[BM * BK]; // 8 KB
    __shared__ unsigned short Bs[BN * BK]; // 8 KB
    __shared__ float sblk[BN];
    const int tid  = threadIdx.x;
    const int wave = tid >> 6;
    const int lane = tid & 63;
    const int wr = wave >> 1, wc = wave & 1;

    // XCD-aware swizzle: consecutive logical tiles (sharing the A panel) land
    // on the same XCD's L2. gridDim.x divisible by 8.
    const int wg    = blockIdx.x;
    const int chunk = gridDim.x >> 3;
    const int swz   = (wg & 7) * chunk + (wg >> 3);
    const int nbn   = N >> 7;
    const int bn    = swz % nbn;
    const int bm    = swz / nbn;

    if (ACCUM_S) {
        for (int i = tid; i < BN; i += 256) sblk[i] = 0.f;
    }

    f32x4 acc[4][4] = {};

    const int lrow = lane >> 2;        // 0..15 (row within 16-row segment)
    const int lcol = (lane & 3) * 8;   // k element offset 0,8,16,24

    const unsigned short* Abase = A + (size_t)(bm * BM) * K;
    const unsigned short* Bbase = B + (size_t)(bn * BN) * K;

    const int kg = (lane >> 4) * 8;    // fragment k offset within BK
    const int fr = lane & 15;          // fragment row

    for (int k0 = 0; k0 < K; k0 += BK) {
        // stage A,B tiles: 8 KB each = 8 segments of 1024B; 2 per wave each
        #pragma unroll
        for (int i = 0; i < 2; ++i) {
            int s = wave * 2 + i;
            const unsigned short* ga = Abase + (size_t)(s * 16 + lrow) * K + (k0 + lcol);
            __builtin_amdgcn_global_load_lds(
                (const __attribute__((address_space(1))) void*)ga,
                (__attribute__((address_space(3))) void*)&As[s * 512], 16, 0, 0);
            const unsigned short* gb = Bbase + (size_t)(s * 16 + lrow) * K + (k0 + lcol);
            __builtin_amdgcn_global_load_lds(
                (const __attribute__((address_space(1))) void*)gb,
                (__attribute__((address_space(3))) void*)&Bs[s * 512], 16, 0, 0);
        }
        __syncthreads();  // drains vmcnt before barrier -> tiles visible

        short8 af[4], bfr[4];
        #pragma unroll
        for (int m = 0; m < 4; ++m) {
            int row = wr * 64 + m * 16 + fr;
            af[m] = *(const short8*)&As[row * BK + kg];
        }
        #pragma unroll
        for (int n = 0; n < 4; ++n) {
            int row = wc * 64 + n * 16 + fr;
            bfr[n] = *(const short8*)&Bs[row * BK + kg];
        }
        #pragma unroll
        for (int m = 0; m < 4; ++m)
            #pragma unroll
            for (int n = 0; n < 4; ++n)
                acc[m][n] = __builtin_amdgcn_mfma_f32_16x16x32_bf16(
                    __builtin_bit_cast(bf16x8, af[m]),
                    __builtin_bit_cast(bf16x8, bfr[n]),
                    acc[m][n], 0, 0, 0);
        __syncthreads();  // all waves done reading before next overwrite
    }

    // epilogue: C/D layout col=lane&15, row=(lane>>4)*4 + j (verified gfx950)
    const int cg = lane & 15;
    const int rg = (lane >> 4) * 4;
    float csum[4] = {};
    #pragma unroll
    for (int m = 0; m < 4; ++m) {
        #pragma unroll
        for (int n = 0; n < 4; ++n) {
            int col = bn * BN + wc * 64 + n * 16 + cg;
            float bv = bias[col];
            #pragma unroll
            for (int j = 0; j < 4; ++j) {
                int row = bm * BM + wr * 64 + m * 16 + rg + j;
                float v = acc[m][n][j] + bv;
                C[(size_t)row * N + col] = v;
                if (ACCUM_S) csum[n] += v * v;
            }
        }
    }
    if (ACCUM_S) {
        __syncthreads();  // sblk zeroed by all
        #pragma unroll
        for (int n = 0; n < 4; ++n)
            atomicAdd(&sblk[wc * 64 + n * 16 + cg], csum[n]);
        __syncthreads();
        // rows of this block all belong to batch b = (bm*BM)/T
        const int b = (bm * BM) >> 12;
        for (int i = tid; i < BN; i += 256)
            atomicAdd(&S[b * CC + bn * BN + i], sblk[i]);
    }
}

// ---------------- per-row: tmp, head-softmax Pi, accumulate sumPi & dotsU ----------------
// One wave per token row (1024 f32, contiguous). 4 waves/block, 8 rows/wave.
__global__ __launch_bounds__(256)
void k_row_softmax(const float* __restrict__ w, const float* __restrict__ S,
                   const float* __restrict__ temp,
                   float* __restrict__ Pi, float* __restrict__ dotsU,
                   float* __restrict__ sumPi)
{
    __shared__ float dots_local[CC];
    __shared__ float sPi_local[HH];
    const int tid  = threadIdx.x;
    const int wave = tid >> 6;
    const int lane = tid & 63;
    const int b    = blockIdx.x >> 7;   // 128 blocks per batch
    const int tile = blockIdx.x & 127;

    for (int c = tid; c < CC; c += 256) dots_local[c] = 0.f;
    if (tid < HH) sPi_local[tid] = 0.f;
    __syncthreads();

    const int g  = lane >> 4;   // 16-lane group -> sub-head index
    const int li = lane & 15;

    // chunk q covers c = q*256 + lane*4 .. +3 ; head(q,g) = q*4+g
    float inv[4][4];
    float tsc[4];
    #pragma unroll
    for (int q = 0; q < 4; ++q) {
        int c = q * 256 + lane * 4;
        float4 sv = *(const float4*)&S[b * CC + c];
        inv[q][0] = 1.f / fmaxf(sv.x, 1e-24f);
        inv[q][1] = 1.f / fmaxf(sv.y, 1e-24f);
        inv[q][2] = 1.f / fmaxf(sv.z, 1e-24f);
        inv[q][3] = 1.f / fmaxf(sv.w, 1e-24f);
        tsc[q] = temp[q * 4 + g];
    }

    float dacc[4][4] = {};
    float sPiAcc[4] = {};

    for (int i = 0; i < 8; ++i) {
        int t = tile * 32 + wave * 8 + i;
        const float* row = w + ((size_t)b * TT + t) * CC;
        float4 wv[4];
        float pq[4];
        #pragma unroll
        for (int q = 0; q < 4; ++q) {
            wv[q] = *(const float4*)&row[q * 256 + lane * 4];
            pq[q] = wv[q].x * wv[q].x * inv[q][0] + wv[q].y * wv[q].y * inv[q][1]
                  + wv[q].z * wv[q].z * inv[q][2] + wv[q].w * wv[q].w * inv[q][3];
        }
        // reduce over the 16 lanes of each group -> per-head sum_d w_normed^2
        #pragma unroll
        for (int off = 1; off < 16; off <<= 1) {
            #pragma unroll
            for (int q = 0; q < 4; ++q) pq[q] += __shfl_xor(pq[q], off);
        }
        float mx = -1e30f;
        #pragma unroll
        for (int q = 0; q < 4; ++q) { pq[q] *= tsc[q]; mx = fmaxf(mx, pq[q]); }
        mx = fmaxf(mx, __shfl_xor(mx, 16));
        mx = fmaxf(mx, __shfl_xor(mx, 32));
        float e[4], ssum = 0.f;
        #pragma unroll
        for (int q = 0; q < 4; ++q) { e[q] = __expf(pq[q] - mx); ssum += e[q]; }
        ssum += __shfl_xor(ssum, 16);
        ssum += __shfl_xor(ssum, 32);
        float rs = 1.f / ssum;
        #pragma unroll
        for (int q = 0; q < 4; ++q) {
            float piq = e[q] * rs;
            dacc[q][0] += piq * wv[q].x * wv[q].x;
            dacc[q][1] += piq * wv[q].y * wv[q].y;
            dacc[q][2] += piq * wv[q].z * wv[q].z;
            dacc[q][3] += piq * wv[q].w * wv[q].w;
            if (li == 0) {
                Pi[((size_t)(b * HH + q * 4 + g)) * TT + t] = piq;
                sPiAcc[q] += piq;
            }
        }
    }

    #pragma unroll
    for (int q = 0; q < 4; ++q) {
        int c = q * 256 + lane * 4;
        atomicAdd(&dots_local[c + 0], dacc[q][0]);
        atomicAdd(&dots_local[c + 1], dacc[q][1]);
        atomicAdd(&dots_local[c + 2], dacc[q][2]);
        atomicAdd(&dots_local[c + 3], dacc[q][3]);
        if (li == 0) atomicAdd(&sPi_local[q * 4 + g], sPiAcc[q]);
    }
    __syncthreads();
    for (int c = tid; c < CC; c += 256) atomicAdd(&dotsU[b * CC + c], dots_local[c]);
    if (tid < HH) atomicAdd(&sumPi[b * HH + tid], sPi_local[tid]);
}

// ---------------- attnScale[b,c] = 1/(1 + dotsU/(sumPi+1e-8)) ----------------
__global__ void k_attnscale(const float* __restrict__ dotsU,
                            const float* __restrict__ sumPi,
                            float* __restrict__ attnScale) {
    int i = blockIdx.x * 256 + threadIdx.x;   // over B*C = 4096
    if (i >= BB * CC) return;
    int b = i >> 10;
    int h = (i >> 6) & 15;
    float sp = sumPi[b * HH + h] + 1e-8f;
    attnScale[i] = 1.f / (1.f + dotsU[i] / sp);
}

// ---------------- y[b,t,c] = bf16( -(w*Pi[b,h,t]) * attnScale[b,c] ) ----------------
__global__ void k_make_y(const float* __restrict__ w, const float* __restrict__ Pi,
                         const float* __restrict__ attnScale,
                         unsigned short* __restrict__ y)
{
    size_t i = (size_t)blockIdx.x * 256 + threadIdx.x;  // float4 chunk id
    size_t flat = i * 4;
    int c = (int)(flat & (CC - 1));
    size_t bt = flat >> 10;         // b*T + t
    int t = (int)(bt & (TT - 1));
    int b = (int)(bt >> 12);
    int h = c >> 6;
    float pi = Pi[((size_t)(b * HH + h)) * TT + t];
    float4 wv = *(const float4*)&w[flat];
    float4 av = *(const float4*)&attnScale[b * CC + c];
    ushort4 o;
    o.x = f2bf(-(wv.x * pi) * av.x);
    o.y = f2bf(-(wv.y * pi) * av.y);
    o.z = f2bf(-(wv.z * pi) * av.z);
    o.w = f2bf(-(wv.w * pi) * av.w);
    *(ushort4*)&y[flat] = o;
}

// ---------------- launch ----------------
extern "C" void kernel_launch(void* const* d_in, const int* in_sizes, int n_in,
                              void* d_out, int out_size, void* d_ws, size_t ws_size,
                              hipStream_t stream) {
    const float* x      = (const float*)d_in[0];
    const float* W_attn = (const float*)d_in[1];
    const float* b_attn = (const float*)d_in[2];
    const float* W_proj = (const float*)d_in[3];
    const float* b_proj = (const float*)d_in[4];
    const float* temp   = (const float*)d_in[5];
    // d_in[6] = n_head (16), hard-coded

    char* ws = (char*)d_ws;
    unsigned short* xy_bf16 = (unsigned short*)(ws);             // 33554432 B (x, later y)
    unsigned short* Wa_bf16 = (unsigned short*)(ws + 33554432);  // 2097152 B
    unsigned short* Wp_bf16 = (unsigned short*)(ws + 35651584);  // 2097152 B
    float* Pi        = (float*)(ws + 37748736);  // 1048576 B
    float* S         = (float*)(ws + 38797312);  // 16384 B
    float* dotsU     = (float*)(ws + 38813696);  // 16384 B
    float* sumPi     = (float*)(ws + 38830080);  // 256 B
    float* attnScale = (float*)(ws + 38830336);  // 16384 B
    float* wbuf = (float*)d_out;  // (B,T,C) fp32 intermediate lives in d_out

    // convert inputs to bf16
    k_f32_to_bf16<<<dim3(16384), dim3(256), 0, stream>>>(x, xy_bf16, 4194304);
    k_f32_to_bf16<<<dim3(1024), dim3(256), 0, stream>>>(W_attn, Wa_bf16, 262144);
    k_f32_to_bf16<<<dim3(1024), dim3(256), 0, stream>>>(W_proj, Wp_bf16, 262144);

    // zero accumulators (S, dotsU, sumPi are contiguous: 16384+16384+256)
    hipMemsetAsync(S, 0, 16384 + 16384 + 256, stream);

    // GEMM1: w = x @ W_attn^T + b_attn  -> d_out (fp32); also S[b,c] = sum_t w^2
    k_gemm_bt_bias<1><<<dim3(1024), dim3(256), 0, stream>>>(
        xy_bf16, Wa_bf16, b_attn, wbuf, S, BB * TT, CC, CC);

    // per-row softmax over heads + accumulate sumPi, dotsU
    k_row_softmax<<<dim3(512), dim3(256), 0, stream>>>(wbuf, S, temp, Pi, dotsU, sumPi);

    // attn scale
    k_attnscale<<<dim3(16), dim3(256), 0, stream>>>(dotsU, sumPi, attnScale);

    // y (bf16) overwrites x_bf16 region
    k_make_y<<<dim3(16384), dim3(256), 0, stream>>>(wbuf, Pi, attnScale, xy_bf16);

    // GEMM2: out = y @ W_proj^T + b_proj -> d_out (fp32)
    k_gemm_bt_bias<0><<<dim3(1024), dim3(256), 0, stream>>>(
        xy_bf16, Wp_bf16, b_proj, (float*)d_out, nullptr, BB * TT, CC, CC);
}

// Round 3
// 185.177 us; speedup vs baseline: 1.0684x; 1.0064x over previous
//
#include <hip/hip_runtime.h>
#include <hip/hip_bf16.h>

// Problem constants: B=4, T=4096, C=1024, H=16, D=64
#define BB 4
#define TT 4096
#define CC 1024
#define HH 16
#define DD 64

typedef __attribute__((ext_vector_type(8))) short short8;
typedef __attribute__((ext_vector_type(8))) __bf16 bf16x8;
typedef __attribute__((ext_vector_type(4))) float f32x4;

static __device__ __forceinline__ unsigned short f2bf(float f) {
    unsigned int u = __builtin_bit_cast(unsigned int, f);
    unsigned int r = (u + 0x7FFFu + ((u >> 16) & 1u)) >> 16;
    return (unsigned short)r;
}

// ---------------- fp32 -> bf16 conversion (vectorized) ----------------
__global__ void k_f32_to_bf16(const float* __restrict__ src,
                              unsigned short* __restrict__ dst, int n4) {
    int i = blockIdx.x * 256 + threadIdx.x;
    if (i >= n4) return;
    float4 v = ((const float4*)src)[i];
    ushort4 o;
    o.x = f2bf(v.x); o.y = f2bf(v.y); o.z = f2bf(v.z); o.w = f2bf(v.w);
    ((ushort4*)dst)[i] = o;
}

// ================= 256x256 deep-pipelined bf16 GEMM =================
// C[m,n] = sum_k A[m,k]*B[n,k] + bias[n];  A: MxK, B: NxK (row-major bf16).
// 8 waves (2 Mx4 N), per-wave output 128x64. BK=64, double-buffered LDS
// (2 x (A 32KB + B 32KB) = 128KB). Counted vmcnt(8) pipeline: tile kt+2's
// staging loads stay in flight across the barriers while kt computes.
// LDS XOR-swizzle (byte ^= (row&7)<<4) on the read side; staging loads the
// inverse-permuted global 16B chunk into a linear LDS dest (global_load_lds
// requires linear dest).
#define GBM 256
#define GBN 256
#define GBK 64

// stage one 256x64 bf16 tile (32KB): 4 passes x 512 threads x 16B.
// chunk = p*512 + wave*64 + lane; r = chunk/8, j = chunk%8; source 16B-chunk
// within the row is j ^ (r&7) (inverse of the read swizzle).
static __device__ __forceinline__ void stage_tile(
    const unsigned short* __restrict__ Gbase, unsigned short* lbuf,
    int k0, int K, int wave, int lane)
{
    #pragma unroll
    for (int p = 0; p < 4; ++p) {
        int chunk = p * 512 + wave * 64 + lane;
        int r = chunk >> 3;
        int j = chunk & 7;
        int srcj = j ^ (r & 7);
        const unsigned short* g = Gbase + (size_t)r * K + (k0 + srcj * 8);
        __builtin_amdgcn_global_load_lds(
            (const __attribute__((address_space(1))) void*)g,
            (__attribute__((address_space(3))) void*)(lbuf + (size_t)(p * 512 + wave * 64) * 8),
            16, 0, 0);
    }
}

template<int ACCUM_S>
__global__ __launch_bounds__(512, 2)
void k_gemm256(const unsigned short* __restrict__ A,
               const unsigned short* __restrict__ B,
               const float* __restrict__ bias,
               float* __restrict__ C,
               float* __restrict__ S,
               int M, int N, int K)
{
    __shared__ unsigned short Abuf[2][GBM * GBK]; // 2 x 32KB
    __shared__ unsigned short Bbuf[2][GBN * GBK]; // 2 x 32KB
    const int tid  = threadIdx.x;
    const int wave = tid >> 6;
    const int lane = tid & 63;
    const int wr = wave >> 2;   // 0..1
    const int wc = wave & 3;    // 0..3
    const int fr = lane & 15;
    const int hi = lane >> 4;   // 0..3

    // XCD-aware bijective swizzle (256 blocks, 8 XCDs, chunk=32, bn fastest)
    const int wg  = blockIdx.x;
    const int swz = (wg & 7) * 32 + (wg >> 3);
    const int bn  = swz & 3;
    const int bm  = swz >> 2;

    const unsigned short* Abase = A + (size_t)(bm * GBM) * K;
    const unsigned short* Bbase = B + (size_t)(bn * GBN) * K;

    const int nt = K / GBK;   // 16

    f32x4 acc[8][4] = {};

    // ---- prologue: stage tiles 0 and 1 ----
    stage_tile(Abase, Abuf[0], 0, K, wave, lane);
    stage_tile(Bbase, Bbuf[0], 0, K, wave, lane);
    stage_tile(Abase, Abuf[1], GBK, K, wave, lane);
    stage_tile(Bbase, Bbuf[1], GBK, K, wave, lane);
    asm volatile("s_waitcnt vmcnt(8)" ::: "memory");   // tile 0's 8 loads done
    __builtin_amdgcn_s_barrier();

    // precomputed swizzled read offsets (ushort index) pieces
    // A row r = wr*128 + mi*16 + fr ; B row rb = wc*64 + ni*16 + fr
    const int rx = (fr & 7) << 4;  // row-XOR byte pattern (r&7 == fr&7)

    for (int kt = 0; kt < nt; ++kt) {
        const int cur = kt & 1;
        const unsigned short* Ab = Abuf[cur];
        const unsigned short* Bl = Bbuf[cur];

        // ---- read all fragments of buf[cur] into registers ----
        short8 bfrag[4][2];
        #pragma unroll
        for (int ni = 0; ni < 4; ++ni) {
            int r = wc * 64 + ni * 16 + fr;
            #pragma unroll
            for (int ks = 0; ks < 2; ++ks) {
                int cb = ks * 64 + hi * 16;
                bfrag[ni][ks] = *(const short8*)&Bl[r * 64 + ((cb ^ rx) >> 1)];
            }
        }
        short8 afrag[8][2];
        #pragma unroll
        for (int mi = 0; mi < 8; ++mi) {
            int r = wr * 128 + mi * 16 + fr;
            #pragma unroll
            for (int ks = 0; ks < 2; ++ks) {
                int cb = ks * 64 + hi * 16;
                afrag[mi][ks] = *(const short8*)&Ab[r * 64 + ((cb ^ rx) >> 1)];
            }
        }
        asm volatile("s_waitcnt lgkmcnt(0)" ::: "memory");
        __builtin_amdgcn_sched_barrier(0);
        __builtin_amdgcn_s_barrier();      // all waves done reading buf[cur]

        // ---- prefetch tile kt+2 into buf[cur] (redundant re-stage at tail) ----
        const int ktn = (kt + 2 < nt) ? kt + 2 : kt;
        stage_tile(Abase, (unsigned short*)Abuf[cur], ktn * GBK, K, wave, lane);
        stage_tile(Bbase, (unsigned short*)Bbuf[cur], ktn * GBK, K, wave, lane);

        // ---- compute: 64 MFMA ----
        __builtin_amdgcn_s_setprio(1);
        #pragma unroll
        for (int ks = 0; ks < 2; ++ks)
            #pragma unroll
            for (int mi = 0; mi < 8; ++mi)
                #pragma unroll
                for (int ni = 0; ni < 4; ++ni)
                    acc[mi][ni] = __builtin_amdgcn_mfma_f32_16x16x32_bf16(
                        __builtin_bit_cast(bf16x8, afrag[mi][ks]),
                        __builtin_bit_cast(bf16x8, bfrag[ni][ks]),
                        acc[mi][ni], 0, 0, 0);
        __builtin_amdgcn_s_setprio(0);

        // ---- wait for NEXT tile's loads (counted: 8 newest stay in flight) ----
        asm volatile("s_waitcnt vmcnt(8)" ::: "memory");
        __builtin_amdgcn_s_barrier();
    }

    // drain everything (incl. redundant tail stages) before LDS reuse
    __syncthreads();

    // ---- epilogue ----
    const int cg = fr;            // output col within 16
    const int rg = hi * 4;        // output row group
    float* sblk = (float*)&Abuf[0][0];
    if (ACCUM_S) {
        if (tid < GBN) sblk[tid] = 0.f;
        __syncthreads();
    }
    float csum[4] = {};
    #pragma unroll
    for (int mi = 0; mi < 8; ++mi) {
        #pragma unroll
        for (int ni = 0; ni < 4; ++ni) {
            int col = bn * GBN + wc * 64 + ni * 16 + cg;
            float bv = bias[col];
            #pragma unroll
            for (int j = 0; j < 4; ++j) {
                int row = bm * GBM + wr * 128 + mi * 16 + rg + j;
                float v = acc[mi][ni][j] + bv;
                C[(size_t)row * N + col] = v;
                if (ACCUM_S) csum[ni] += v * v;
            }
        }
    }
    if (ACCUM_S) {
        #pragma unroll
        for (int ni = 0; ni < 4; ++ni)
            atomicAdd(&sblk[wc * 64 + ni * 16 + cg], csum[ni]);
        __syncthreads();
        const int b = bm >> 4;   // 16 bm-tiles per batch (4096/256)
        if (tid < GBN) atomicAdd(&S[b * CC + bn * GBN + tid], sblk[tid]);
    }
}

// ---------------- per-row: tmp, head-softmax Pi, accumulate sumPi & dotsU ----------------
__global__ __launch_bounds__(256)
void k_row_softmax(const float* __restrict__ w, const float* __restrict__ S,
                   const float* __restrict__ temp,
                   float* __restrict__ Pi, float* __restrict__ dotsU,
                   float* __restrict__ sumPi)
{
    __shared__ float dots_local[CC];
    __shared__ float sPi_local[HH];
    const int tid  = threadIdx.x;
    const int wave = tid >> 6;
    const int lane = tid & 63;
    const int b    = blockIdx.x >> 7;
    const int tile = blockIdx.x & 127;

    for (int c = tid; c < CC; c += 256) dots_local[c] = 0.f;
    if (tid < HH) sPi_local[tid] = 0.f;
    __syncthreads();

    const int g  = lane >> 4;
    const int li = lane & 15;

    float inv[4][4];
    float tsc[4];
    #pragma unroll
    for (int q = 0; q < 4; ++q) {
        int c = q * 256 + lane * 4;
        float4 sv = *(const float4*)&S[b * CC + c];
        inv[q][0] = 1.f / fmaxf(sv.x, 1e-24f);
        inv[q][1] = 1.f / fmaxf(sv.y, 1e-24f);
        inv[q][2] = 1.f / fmaxf(sv.z, 1e-24f);
        inv[q][3] = 1.f / fmaxf(sv.w, 1e-24f);
        tsc[q] = temp[q * 4 + g];
    }

    float dacc[4][4] = {};
    float sPiAcc[4] = {};

    for (int i = 0; i < 8; ++i) {
        int t = tile * 32 + wave * 8 + i;
        const float* row = w + ((size_t)b * TT + t) * CC;
        float4 wv[4];
        float pq[4];
        #pragma unroll
        for (int q = 0; q < 4; ++q) {
            wv[q] = *(const float4*)&row[q * 256 + lane * 4];
            pq[q] = wv[q].x * wv[q].x * inv[q][0] + wv[q].y * wv[q].y * inv[q][1]
                  + wv[q].z * wv[q].z * inv[q][2] + wv[q].w * wv[q].w * inv[q][3];
        }
        #pragma unroll
        for (int off = 1; off < 16; off <<= 1) {
            #pragma unroll
            for (int q = 0; q < 4; ++q) pq[q] += __shfl_xor(pq[q], off);
        }
        float mx = -1e30f;
        #pragma unroll
        for (int q = 0; q < 4; ++q) { pq[q] *= tsc[q]; mx = fmaxf(mx, pq[q]); }
        mx = fmaxf(mx, __shfl_xor(mx, 16));
        mx = fmaxf(mx, __shfl_xor(mx, 32));
        float e[4], ssum = 0.f;
        #pragma unroll
        for (int q = 0; q < 4; ++q) { e[q] = __expf(pq[q] - mx); ssum += e[q]; }
        ssum += __shfl_xor(ssum, 16);
        ssum += __shfl_xor(ssum, 32);
        float rs = 1.f / ssum;
        #pragma unroll
        for (int q = 0; q < 4; ++q) {
            float piq = e[q] * rs;
            dacc[q][0] += piq * wv[q].x * wv[q].x;
            dacc[q][1] += piq * wv[q].y * wv[q].y;
            dacc[q][2] += piq * wv[q].z * wv[q].z;
            dacc[q][3] += piq * wv[q].w * wv[q].w;
            if (li == 0) {
                Pi[((size_t)(b * HH + q * 4 + g)) * TT + t] = piq;
                sPiAcc[q] += piq;
            }
        }
    }

    #pragma unroll
    for (int q = 0; q < 4; ++q) {
        int c = q * 256 + lane * 4;
        atomicAdd(&dots_local[c + 0], dacc[q][0]);
        atomicAdd(&dots_local[c + 1], dacc[q][1]);
        atomicAdd(&dots_local[c + 2], dacc[q][2]);
        atomicAdd(&dots_local[c + 3], dacc[q][3]);
        if (li == 0) atomicAdd(&sPi_local[q * 4 + g], sPiAcc[q]);
    }
    __syncthreads();
    for (int c = tid; c < CC; c += 256) atomicAdd(&dotsU[b * CC + c], dots_local[c]);
    if (tid < HH) atomicAdd(&sumPi[b * HH + tid], sPi_local[tid]);
}

// ---------------- attnScale[b,c] = 1/(1 + dotsU/(sumPi+1e-8)) ----------------
__global__ void k_attnscale(const float* __restrict__ dotsU,
                            const float* __restrict__ sumPi,
                            float* __restrict__ attnScale) {
    int i = blockIdx.x * 256 + threadIdx.x;
    if (i >= BB * CC) return;
    int b = i >> 10;
    int h = (i >> 6) & 15;
    float sp = sumPi[b * HH + h] + 1e-8f;
    attnScale[i] = 1.f / (1.f + dotsU[i] / sp);
}

// ---------------- y[b,t,c] = bf16( -(w*Pi[b,h,t]) * attnScale[b,c] ) ----------------
__global__ void k_make_y(const float* __restrict__ w, const float* __restrict__ Pi,
                         const float* __restrict__ attnScale,
                         unsigned short* __restrict__ y)
{
    size_t i = (size_t)blockIdx.x * 256 + threadIdx.x;
    size_t flat = i * 4;
    int c = (int)(flat & (CC - 1));
    size_t bt = flat >> 10;
    int t = (int)(bt & (TT - 1));
    int b = (int)(bt >> 12);
    int h = c >> 6;
    float pi = Pi[((size_t)(b * HH + h)) * TT + t];
    float4 wv = *(const float4*)&w[flat];
    float4 av = *(const float4*)&attnScale[b * CC + c];
    ushort4 o;
    o.x = f2bf(-(wv.x * pi) * av.x);
    o.y = f2bf(-(wv.y * pi) * av.y);
    o.z = f2bf(-(wv.z * pi) * av.z);
    o.w = f2bf(-(wv.w * pi) * av.w);
    *(ushort4*)&y[flat] = o;
}

// ---------------- launch ----------------
extern "C" void kernel_launch(void* const* d_in, const int* in_sizes, int n_in,
                              void* d_out, int out_size, void* d_ws, size_t ws_size,
                              hipStream_t stream) {
    const float* x      = (const float*)d_in[0];
    const float* W_attn = (const float*)d_in[1];
    const float* b_attn = (const float*)d_in[2];
    const float* W_proj = (const float*)d_in[3];
    const float* b_proj = (const float*)d_in[4];
    const float* temp   = (const float*)d_in[5];

    char* ws = (char*)d_ws;
    unsigned short* xy_bf16 = (unsigned short*)(ws);             // 32MB (x, later y)
    unsigned short* Wa_bf16 = (unsigned short*)(ws + 33554432);  // 2MB
    unsigned short* Wp_bf16 = (unsigned short*)(ws + 35651584);  // 2MB
    float* Pi        = (float*)(ws + 37748736);  // 1MB
    float* S         = (float*)(ws + 38797312);  // 16KB
    float* dotsU     = (float*)(ws + 38813696);  // 16KB
    float* sumPi     = (float*)(ws + 38830080);  // 256B
    float* attnScale = (float*)(ws + 38830336);  // 16KB
    float* wbuf = (float*)d_out;                 // (B,T,C) fp32 intermediate

    k_f32_to_bf16<<<dim3(16384), dim3(256), 0, stream>>>(x, xy_bf16, 4194304);
    k_f32_to_bf16<<<dim3(1024), dim3(256), 0, stream>>>(W_attn, Wa_bf16, 262144);
    k_f32_to_bf16<<<dim3(1024), dim3(256), 0, stream>>>(W_proj, Wp_bf16, 262144);

    hipMemsetAsync(S, 0, 16384 + 16384 + 256, stream);

    // GEMM1: w = x @ W_attn^T + b_attn ; fused S[b,c] = sum_t w^2
    k_gemm256<1><<<dim3(256), dim3(512), 0, stream>>>(
        xy_bf16, Wa_bf16, b_attn, wbuf, S, BB * TT, CC, CC);

    k_row_softmax<<<dim3(512), dim3(256), 0, stream>>>(wbuf, S, temp, Pi, dotsU, sumPi);

    k_attnscale<<<dim3(16), dim3(256), 0, stream>>>(dotsU, sumPi, attnScale);

    k_make_y<<<dim3(16384), dim3(256), 0, stream>>>(wbuf, Pi, attnScale, xy_bf16);

    // GEMM2: out = y @ W_proj^T + b_proj
    k_gemm256<0><<<dim3(256), dim3(512), 0, stream>>>(
        xy_bf16, Wp_bf16, b_proj, (float*)d_out, nullptr, BB * TT, CC, CC);
}

// Round 4
// 152.145 us; speedup vs baseline: 1.3004x; 1.2171x over previous
//
#include <hip/hip_runtime.h>
#include <hip/hip_bf16.h>

// Problem constants: B=4, T=4096, C=1024, H=16, D=64
#define BB 4
#define TT 4096
#define CC 1024
#define HH 16
#define DD 64

typedef __attribute__((ext_vector_type(8))) short short8;
typedef __attribute__((ext_vector_type(8))) __bf16 bf16x8;
typedef __attribute__((ext_vector_type(4))) float f32x4;

static __device__ __forceinline__ unsigned short f2bf(float f) {
    unsigned int u = __builtin_bit_cast(unsigned int, f);
    unsigned int r = (u + 0x7FFFu + ((u >> 16) & 1u)) >> 16;
    return (unsigned short)r;
}

// ---------------- fp32 -> bf16 conversion (vectorized) ----------------
__global__ void k_f32_to_bf16(const float* __restrict__ src,
                              unsigned short* __restrict__ dst, int n4) {
    int i = blockIdx.x * 256 + threadIdx.x;
    if (i >= n4) return;
    float4 v = ((const float4*)src)[i];
    ushort4 o;
    o.x = f2bf(v.x); o.y = f2bf(v.y); o.z = f2bf(v.z); o.w = f2bf(v.w);
    ((ushort4*)dst)[i] = o;
}

// ================= 256x256 phase-pipelined bf16 GEMM =================
// C[m,n] = sum_k A[m,k]*B[n,k] + bias[n];  A: MxK, B: NxK row-major bf16.
// 8 waves (2M x 4N), per-wave output 128x64. BK=32.
// 4-buffer LDS rotation (4 x 32KB): compute kt from buf[kt&3], stage kt+3
// into buf[(kt+3)&3] (its readers finished at kt-1 -> race-free).
// 2 phases per K-tile, each: {8 ds_read_b128 | 2 global_load_lds -> barrier
// -> lgkmcnt(0) -> setprio(1) 16 MFMA setprio(0) -> barrier}; one counted
// vmcnt(8) per K-tile (3 tiles in flight, never drained in-loop).
// LDS rows are 64B; rotate-swizzle slot=(hi+(r>>1))&3 -> 2-way bank alias
// (free). Staging writes linear LDS dest with inverse-permuted global src.
#define GBM 256
#define GBN 256
#define GBK 32

// stage one 256x32 bf16 tile (16KB): 8 waves x 2 issues x 64 lanes x 16B.
// LDS chunk c=(wave*2+q)*64+lane -> r=c>>2, slot j=c&3 holds global k-chunk
// (j-(r>>1))&3  (inverse of read swizzle slot=(hi+(r>>1))&3).
static __device__ __forceinline__ void stage_tile32(
    const unsigned short* __restrict__ Gbase, unsigned short* lbase,
    int k0, int K, int wave, int lane)
{
    #pragma unroll
    for (int q = 0; q < 2; ++q) {
        int c = (wave * 2 + q) * 64 + lane;
        int r = c >> 2;
        int j = c & 3;
        int srcj = (j - (r >> 1)) & 3;
        const unsigned short* g = Gbase + (size_t)r * K + k0 + srcj * 8;
        __builtin_amdgcn_global_load_lds(
            (const __attribute__((address_space(1))) void*)g,
            (__attribute__((address_space(3))) void*)(lbase + (wave * 2 + q) * 512),
            16, 0, 0);
    }
}

template<int ACCUM_S>
__global__ __launch_bounds__(512, 2)
void k_gemm256(const unsigned short* __restrict__ A,
               const unsigned short* __restrict__ B,
               const float* __restrict__ bias,
               float* __restrict__ C,
               float* __restrict__ S,
               int M, int N, int K)
{
    // per buffer: A tile [256][32] = 8192 ushorts, then B tile 8192 ushorts
    __shared__ unsigned short lds[4][16384];   // 128 KB
    const int tid  = threadIdx.x;
    const int wave = tid >> 6;
    const int lane = tid & 63;
    const int wr = wave >> 2;   // 0..1
    const int wc = wave & 3;    // 0..3
    const int fr = lane & 15;
    const int hi = lane >> 4;   // 0..3

    // XCD-aware bijective swizzle (256 blocks, 8 XCDs, chunk=32, bn fastest)
    const int wg  = blockIdx.x;
    const int swz = (wg & 7) * 32 + (wg >> 3);
    const int bn  = swz & 3;
    const int bm  = swz >> 2;

    const unsigned short* Abase = A + (size_t)(bm * GBM) * K;
    const unsigned short* Bbase = B + (size_t)(bn * GBN) * K;

    const int nt = K / GBK;   // 32

    // per-lane constant read offsets (ushort idx):
    // slot = (hi + (fr>>1)) & 3 (independent of mi/ni/wr/wc)
    const int sl   = (hi + (fr >> 1)) & 3;
    const int aoff = (wr * 128 + fr) * 32 + sl * 8;          // + mi*512
    const int boff = 8192 + (wc * 64 + fr) * 32 + sl * 8;    // + ni*512

    f32x4 acc[8][4] = {};

    // ---- prologue: stage tiles 0,1,2 ----
    stage_tile32(Abase, lds[0],        0,       K, wave, lane);
    stage_tile32(Bbase, lds[0] + 8192, 0,       K, wave, lane);
    stage_tile32(Abase, lds[1],        GBK,     K, wave, lane);
    stage_tile32(Bbase, lds[1] + 8192, GBK,     K, wave, lane);
    stage_tile32(Abase, lds[2],        2 * GBK, K, wave, lane);
    stage_tile32(Bbase, lds[2] + 8192, 2 * GBK, K, wave, lane);
    asm volatile("s_waitcnt vmcnt(8)" ::: "memory");   // tile 0 landed
    __builtin_amdgcn_s_barrier();

    for (int kt = 0; kt < nt; ++kt) {
        const unsigned short* buf = lds[kt & 3];
        unsigned short* sbuf = lds[(kt + 3) & 3];
        int k3 = kt + 3; if (k3 >= nt) k3 = nt - 1;

        // ================= phase 0: mi 0..3 =================
        short8 af0[4], bf0[4];
        #pragma unroll
        for (int i = 0; i < 4; ++i) af0[i] = *(const short8*)&buf[aoff + i * 512];
        #pragma unroll
        for (int i = 0; i < 4; ++i) bf0[i] = *(const short8*)&buf[boff + i * 512];
        stage_tile32(Abase, sbuf, k3 * GBK, K, wave, lane);
        __builtin_amdgcn_s_barrier();
        asm volatile("s_waitcnt lgkmcnt(0)" ::: "memory");
        __builtin_amdgcn_s_setprio(1);
        #pragma unroll
        for (int mi = 0; mi < 4; ++mi)
            #pragma unroll
            for (int ni = 0; ni < 4; ++ni)
                acc[mi][ni] = __builtin_amdgcn_mfma_f32_16x16x32_bf16(
                    __builtin_bit_cast(bf16x8, af0[mi]),
                    __builtin_bit_cast(bf16x8, bf0[ni]),
                    acc[mi][ni], 0, 0, 0);
        __builtin_amdgcn_s_setprio(0);
        __builtin_amdgcn_s_barrier();

        // ================= phase 1: mi 4..7 =================
        short8 af1[4], bf1[4];
        #pragma unroll
        for (int i = 0; i < 4; ++i) af1[i] = *(const short8*)&buf[aoff + (4 + i) * 512];
        #pragma unroll
        for (int i = 0; i < 4; ++i) bf1[i] = *(const short8*)&buf[boff + i * 512];
        stage_tile32(Bbase, sbuf + 8192, k3 * GBK, K, wave, lane);
        // counted wait, once per K-tile: guarantees tile kt+1 fully landed
        // (after it: tiles kt+2,kt+3 = 8 loads/thread remain in flight)
        asm volatile("s_waitcnt vmcnt(8)" ::: "memory");
        __builtin_amdgcn_s_barrier();
        asm volatile("s_waitcnt lgkmcnt(0)" ::: "memory");
        __builtin_amdgcn_s_setprio(1);
        #pragma unroll
        for (int mi = 0; mi < 4; ++mi)
            #pragma unroll
            for (int ni = 0; ni < 4; ++ni)
                acc[4 + mi][ni] = __builtin_amdgcn_mfma_f32_16x16x32_bf16(
                    __builtin_bit_cast(bf16x8, af1[mi]),
                    __builtin_bit_cast(bf16x8, bf1[ni]),
                    acc[4 + mi][ni], 0, 0, 0);
        __builtin_amdgcn_s_setprio(0);
        __builtin_amdgcn_s_barrier();
    }

    __syncthreads();   // full drain before LDS reuse

    // ---- epilogue ----
    const int cg = fr;            // output col within 16
    const int rg = hi * 4;        // output row group
    float* sblk = (float*)&lds[0][0];
    if (ACCUM_S) {
        if (tid < GBN) sblk[tid] = 0.f;
        __syncthreads();
    }
    float csum[4] = {};
    #pragma unroll
    for (int mi = 0; mi < 8; ++mi) {
        #pragma unroll
        for (int ni = 0; ni < 4; ++ni) {
            int col = bn * GBN + wc * 64 + ni * 16 + cg;
            float bv = bias[col];
            #pragma unroll
            for (int j = 0; j < 4; ++j) {
                int row = bm * GBM + wr * 128 + mi * 16 + rg + j;
                float v = acc[mi][ni][j] + bv;
                C[(size_t)row * N + col] = v;
                if (ACCUM_S) csum[ni] += v * v;
            }
        }
    }
    if (ACCUM_S) {
        #pragma unroll
        for (int ni = 0; ni < 4; ++ni)
            atomicAdd(&sblk[wc * 64 + ni * 16 + cg], csum[ni]);
        __syncthreads();
        const int b = bm >> 4;   // 16 bm-tiles per batch (4096/256)
        if (tid < GBN) atomicAdd(&S[b * CC + bn * GBN + tid], sblk[tid]);
    }
}

// ---------------- per-row: tmp, head-softmax Pi, accumulate sumPi & dotsU ----------------
__global__ __launch_bounds__(256)
void k_row_softmax(const float* __restrict__ w, const float* __restrict__ S,
                   const float* __restrict__ temp,
                   float* __restrict__ Pi, float* __restrict__ dotsU,
                   float* __restrict__ sumPi)
{
    __shared__ float dots_local[CC];
    __shared__ float sPi_local[HH];
    const int tid  = threadIdx.x;
    const int wave = tid >> 6;
    const int lane = tid & 63;
    const int b    = blockIdx.x >> 7;
    const int tile = blockIdx.x & 127;

    for (int c = tid; c < CC; c += 256) dots_local[c] = 0.f;
    if (tid < HH) sPi_local[tid] = 0.f;
    __syncthreads();

    const int g  = lane >> 4;
    const int li = lane & 15;

    float inv[4][4];
    float tsc[4];
    #pragma unroll
    for (int q = 0; q < 4; ++q) {
        int c = q * 256 + lane * 4;
        float4 sv = *(const float4*)&S[b * CC + c];
        inv[q][0] = 1.f / fmaxf(sv.x, 1e-24f);
        inv[q][1] = 1.f / fmaxf(sv.y, 1e-24f);
        inv[q][2] = 1.f / fmaxf(sv.z, 1e-24f);
        inv[q][3] = 1.f / fmaxf(sv.w, 1e-24f);
        tsc[q] = temp[q * 4 + g];
    }

    float dacc[4][4] = {};
    float sPiAcc[4] = {};

    for (int i = 0; i < 8; ++i) {
        int t = tile * 32 + wave * 8 + i;
        const float* row = w + ((size_t)b * TT + t) * CC;
        float4 wv[4];
        float pq[4];
        #pragma unroll
        for (int q = 0; q < 4; ++q) {
            wv[q] = *(const float4*)&row[q * 256 + lane * 4];
            pq[q] = wv[q].x * wv[q].x * inv[q][0] + wv[q].y * wv[q].y * inv[q][1]
                  + wv[q].z * wv[q].z * inv[q][2] + wv[q].w * wv[q].w * inv[q][3];
        }
        #pragma unroll
        for (int off = 1; off < 16; off <<= 1) {
            #pragma unroll
            for (int q = 0; q < 4; ++q) pq[q] += __shfl_xor(pq[q], off);
        }
        float mx = -1e30f;
        #pragma unroll
        for (int q = 0; q < 4; ++q) { pq[q] *= tsc[q]; mx = fmaxf(mx, pq[q]); }
        mx = fmaxf(mx, __shfl_xor(mx, 16));
        mx = fmaxf(mx, __shfl_xor(mx, 32));
        float e[4], ssum = 0.f;
        #pragma unroll
        for (int q = 0; q < 4; ++q) { e[q] = __expf(pq[q] - mx); ssum += e[q]; }
        ssum += __shfl_xor(ssum, 16);
        ssum += __shfl_xor(ssum, 32);
        float rs = 1.f / ssum;
        #pragma unroll
        for (int q = 0; q < 4; ++q) {
            float piq = e[q] * rs;
            dacc[q][0] += piq * wv[q].x * wv[q].x;
            dacc[q][1] += piq * wv[q].y * wv[q].y;
            dacc[q][2] += piq * wv[q].z * wv[q].z;
            dacc[q][3] += piq * wv[q].w * wv[q].w;
            if (li == 0) {
                Pi[((size_t)(b * HH + q * 4 + g)) * TT + t] = piq;
                sPiAcc[q] += piq;
            }
        }
    }

    #pragma unroll
    for (int q = 0; q < 4; ++q) {
        int c = q * 256 + lane * 4;
        atomicAdd(&dots_local[c + 0], dacc[q][0]);
        atomicAdd(&dots_local[c + 1], dacc[q][1]);
        atomicAdd(&dots_local[c + 2], dacc[q][2]);
        atomicAdd(&dots_local[c + 3], dacc[q][3]);
        if (li == 0) atomicAdd(&sPi_local[q * 4 + g], sPiAcc[q]);
    }
    __syncthreads();
    for (int c = tid; c < CC; c += 256) atomicAdd(&dotsU[b * CC + c], dots_local[c]);
    if (tid < HH) atomicAdd(&sumPi[b * HH + tid], sPi_local[tid]);
}

// ---------------- attnScale[b,c] = 1/(1 + dotsU/(sumPi+1e-8)) ----------------
__global__ void k_attnscale(const float* __restrict__ dotsU,
                            const float* __restrict__ sumPi,
                            float* __restrict__ attnScale) {
    int i = blockIdx.x * 256 + threadIdx.x;
    if (i >= BB * CC) return;
    int b = i >> 10;
    int h = (i >> 6) & 15;
    float sp = sumPi[b * HH + h] + 1e-8f;
    attnScale[i] = 1.f / (1.f + dotsU[i] / sp);
}

// ---------------- y[b,t,c] = bf16( -(w*Pi[b,h,t]) * attnScale[b,c] ) ----------------
__global__ void k_make_y(const float* __restrict__ w, const float* __restrict__ Pi,
                         const float* __restrict__ attnScale,
                         unsigned short* __restrict__ y)
{
    size_t i = (size_t)blockIdx.x * 256 + threadIdx.x;
    size_t flat = i * 4;
    int c = (int)(flat & (CC - 1));
    size_t bt = flat >> 10;
    int t = (int)(bt & (TT - 1));
    int b = (int)(bt >> 12);
    int h = c >> 6;
    float pi = Pi[((size_t)(b * HH + h)) * TT + t];
    float4 wv = *(const float4*)&w[flat];
    float4 av = *(const float4*)&attnScale[b * CC + c];
    ushort4 o;
    o.x = f2bf(-(wv.x * pi) * av.x);
    o.y = f2bf(-(wv.y * pi) * av.y);
    o.z = f2bf(-(wv.z * pi) * av.z);
    o.w = f2bf(-(wv.w * pi) * av.w);
    *(ushort4*)&y[flat] = o;
}

// ---------------- launch ----------------
extern "C" void kernel_launch(void* const* d_in, const int* in_sizes, int n_in,
                              void* d_out, int out_size, void* d_ws, size_t ws_size,
                              hipStream_t stream) {
    const float* x      = (const float*)d_in[0];
    const float* W_attn = (const float*)d_in[1];
    const float* b_attn = (const float*)d_in[2];
    const float* W_proj = (const float*)d_in[3];
    const float* b_proj = (const float*)d_in[4];
    const float* temp   = (const float*)d_in[5];

    char* ws = (char*)d_ws;
    unsigned short* xy_bf16 = (unsigned short*)(ws);             // 32MB (x, later y)
    unsigned short* Wa_bf16 = (unsigned short*)(ws + 33554432);  // 2MB
    unsigned short* Wp_bf16 = (unsigned short*)(ws + 35651584);  // 2MB
    float* Pi        = (float*)(ws + 37748736);  // 1MB
    float* S         = (float*)(ws + 38797312);  // 16KB
    float* dotsU     = (float*)(ws + 38813696);  // 16KB
    float* sumPi     = (float*)(ws + 38830080);  // 256B
    float* attnScale = (float*)(ws + 38830336);  // 16KB
    float* wbuf = (float*)d_out;                 // (B,T,C) fp32 intermediate

    k_f32_to_bf16<<<dim3(16384), dim3(256), 0, stream>>>(x, xy_bf16, 4194304);
    k_f32_to_bf16<<<dim3(1024), dim3(256), 0, stream>>>(W_attn, Wa_bf16, 262144);
    k_f32_to_bf16<<<dim3(1024), dim3(256), 0, stream>>>(W_proj, Wp_bf16, 262144);

    hipMemsetAsync(S, 0, 16384 + 16384 + 256, stream);

    // GEMM1: w = x @ W_attn^T + b_attn ; fused S[b,c] = sum_t w^2
    k_gemm256<1><<<dim3(256), dim3(512), 0, stream>>>(
        xy_bf16, Wa_bf16, b_attn, wbuf, S, BB * TT, CC, CC);

    k_row_softmax<<<dim3(512), dim3(256), 0, stream>>>(wbuf, S, temp, Pi, dotsU, sumPi);

    k_attnscale<<<dim3(16), dim3(256), 0, stream>>>(dotsU, sumPi, attnScale);

    k_make_y<<<dim3(16384), dim3(256), 0, stream>>>(wbuf, Pi, attnScale, xy_bf16);

    // GEMM2: out = y @ W_proj^T + b_proj
    k_gemm256<0><<<dim3(256), dim3(512), 0, stream>>>(
        xy_bf16, Wp_bf16, b_proj, (float*)d_out, nullptr, BB * TT, CC, CC);
}

// Round 7
// 150.630 us; speedup vs baseline: 1.3135x; 1.0101x over previous
//
#include <hip/hip_runtime.h>
#include <hip/hip_bf16.h>

// Problem constants: B=4, T=4096, C=1024, H=16, D=64
#define BB 4
#define TT 4096
#define CC 1024
#define HH 16
#define DD 64

typedef __attribute__((ext_vector_type(8))) short short8;
typedef __attribute__((ext_vector_type(8))) __bf16 bf16x8;
typedef __attribute__((ext_vector_type(4))) float f32x4;

static __device__ __forceinline__ unsigned short f2bf(float f) {
    unsigned int u = __builtin_bit_cast(unsigned int, f);
    unsigned int r = (u + 0x7FFFu + ((u >> 16) & 1u)) >> 16;
    return (unsigned short)r;
}
static __device__ __forceinline__ float bf2f(unsigned short h) {
    return __builtin_bit_cast(float, ((unsigned int)h) << 16);
}
// 8 floats -> bf16x8 (compiler emits v_cvt_pk_bf16_f32 pairs)
static __device__ __forceinline__ bf16x8 cvt8(f32x4 a, f32x4 b) {
    bf16x8 r;
    r[0] = (__bf16)a[0]; r[1] = (__bf16)a[1]; r[2] = (__bf16)a[2]; r[3] = (__bf16)a[3];
    r[4] = (__bf16)b[0]; r[5] = (__bf16)b[1]; r[6] = (__bf16)b[2]; r[7] = (__bf16)b[3];
    return r;
}

// ---------------- fp32 -> bf16 conversion (weights) ----------------
__global__ void k_f32_to_bf16(const float* __restrict__ src,
                              unsigned short* __restrict__ dst, int n4) {
    int i = blockIdx.x * 256 + threadIdx.x;
    if (i >= n4) return;
    float4 v = ((const float4*)src)[i];
    ushort4 o;
    o.x = f2bf(v.x); o.y = f2bf(v.y); o.z = f2bf(v.z); o.w = f2bf(v.w);
    ((ushort4*)dst)[i] = o;
}

// ================= 256x256 phase-pipelined GEMM =================
// C[m,n] = sum_k A[m,k]*B[n,k] + bias[n]; B: NxK row-major bf16.
// MODE 0: A = fp32 (x), staged as fp32 in LDS, cvt->bf16 at fragment read;
//         C written as bf16 (w16) plus column sum-of-squares S.
// MODE 1: A = bf16 (y16); C written fp32.
// 8 waves (2Mx4N), BK=32, 3-buffer rotation for both A and B, staged 2 tiles
// ahead, one counted vmcnt per K-tile (6 for MODE0: A4+B2; 4 for MODE1: A2+B2).
// All staging via global_load_lds (compiler-visible); LDS XOR-swizzle on 16B
// sub-chunks, inverse-permuted global src + linear LDS dest (rule #21).
#define GBM 256
#define GBN 256
#define GBK 32

// bf16 256x32 tile (16KB): 1024 chunks of 16B; chunk c: r=c>>2, slot j=c&3
// holds global k-chunk (j-(r>>1))&3  (inverse of read slot=(hi+(fr>>1))&3).
static __device__ __forceinline__ void stage_b16(
    const unsigned short* __restrict__ Gbase, unsigned short* lbase,
    int k0, int K, int wave, int lane)
{
    #pragma unroll
    for (int q = 0; q < 2; ++q) {
        int c = (wave * 2 + q) * 64 + lane;
        int r = c >> 2;
        int j = c & 3;
        int srcj = (j - (r >> 1)) & 3;
        const unsigned short* g = Gbase + (size_t)r * K + k0 + srcj * 8;
        __builtin_amdgcn_global_load_lds(
            (const __attribute__((address_space(1))) void*)g,
            (__attribute__((address_space(3))) void*)(lbase + (wave * 2 + q) * 512),
            16, 0, 0);
    }
}

// fp32 256x32 tile (32KB): 2048 chunks of 16B; chunk c: r=c>>3, slot s=c&7
// holds global 4-float sub-chunk s^(r&7) (inverse of read slot=g^(r&7)).
static __device__ __forceinline__ void stage_a_f32(
    const float* __restrict__ Gbase, float* lbase,
    int k0, int K, int wave, int lane)
{
    #pragma unroll
    for (int q = 0; q < 4; ++q) {
        int c = (wave * 4 + q) * 64 + lane;
        int r = c >> 3;
        int s = c & 7;
        int srcs = s ^ (r & 7);
        const float* g = Gbase + (size_t)r * K + k0 + srcs * 4;
        __builtin_amdgcn_global_load_lds(
            (const __attribute__((address_space(1))) void*)g,
            (__attribute__((address_space(3))) void*)(lbase + (wave * 4 + q) * 256),
            16, 0, 0);
    }
}

template<int MODE>
__global__ __launch_bounds__(512, 2)
void k_gemm256(const void* __restrict__ Asrc,
               const unsigned short* __restrict__ Bsrc,
               const float* __restrict__ bias,
               void* __restrict__ Cout,
               float* __restrict__ S,
               int M, int N, int K)
{
    __shared__ unsigned int Au[3][(MODE == 0) ? 8192 : 4096]; // 96KB / 48KB
    __shared__ unsigned short Bl[3][8192];                    // 48KB
    const int tid  = threadIdx.x;
    const int wave = tid >> 6;
    const int lane = tid & 63;
    const int wr = wave >> 2, wc = wave & 3;
    const int fr = lane & 15, hi = lane >> 4;

    // XCD-aware bijective swizzle (256 blocks, 8 XCDs, chunk=32, bn fastest)
    const int wg  = blockIdx.x;
    const int swz = (wg & 7) * 32 + (wg >> 3);
    const int bn  = swz & 3;
    const int bm  = swz >> 2;
    const int nt  = K / GBK;   // 32

    const float* Afg = (const float*)Asrc + (size_t)(bm * GBM) * K;           // MODE 0
    const unsigned short* Abg = (const unsigned short*)Asrc + (size_t)(bm * GBM) * K; // MODE 1
    const unsigned short* Bbase = Bsrc + (size_t)(bn * GBN) * K;

    f32x4 acc[8][4] = {};

    // ---- prologue: stage tiles 0 and 1 ----
    if (MODE == 0) stage_a_f32(Afg, (float*)Au[0], 0, K, wave, lane);
    else           stage_b16(Abg, (unsigned short*)Au[0], 0, K, wave, lane);
    stage_b16(Bbase, Bl[0], 0, K, wave, lane);
    if (MODE == 0) stage_a_f32(Afg, (float*)Au[1], GBK, K, wave, lane);
    else           stage_b16(Abg, (unsigned short*)Au[1], GBK, K, wave, lane);
    stage_b16(Bbase, Bl[1], GBK, K, wave, lane);
    if (MODE == 0) { asm volatile("s_waitcnt vmcnt(6)" ::: "memory"); }
    else           { asm volatile("s_waitcnt vmcnt(4)" ::: "memory"); }
    __builtin_amdgcn_s_barrier();

    // per-lane read offsets
    const int sl    = (hi + (fr >> 1)) & 3;          // bf16 rotate slot
    const int boff  = (wc * 64 + fr) * 32 + sl * 8;  // B read (ushort idx), +ni*512
    const int aoffB = (wr * 128 + fr) * 32 + sl * 8; // MODE1 A read, +mi*512
    const int sw0   = ((2 * hi)     ^ (fr & 7)) * 4; // MODE0 fp32 slots (float idx)
    const int sw1   = ((2 * hi + 1) ^ (fr & 7)) * 4;
    const int arow  = (wr * 128 + fr) * 32;          // MODE0 row base (float idx), +mi*512

    int rb = 0;
    for (int kt = 0; kt < nt; ++kt) {
        const int wb = (rb == 0) ? 2 : rb - 1;       // (rb+2)%3
        int ks = kt + 2; if (ks >= nt) ks = nt - 1;
        const unsigned short* Bc = Bl[rb];

        // ================= phase 0: mi 0..3 =================
        bf16x8 af0[4]; short8 bfr[4];
        if (MODE == 0) {
            const float* Af = (const float*)Au[rb];
            #pragma unroll
            for (int mi = 0; mi < 4; ++mi) {
                f32x4 lo = *(const f32x4*)&Af[arow + mi * 512 + sw0];
                f32x4 h4 = *(const f32x4*)&Af[arow + mi * 512 + sw1];
                af0[mi] = cvt8(lo, h4);
            }
        } else {
            const unsigned short* Ab = (const unsigned short*)Au[rb];
            #pragma unroll
            for (int mi = 0; mi < 4; ++mi)
                af0[mi] = __builtin_bit_cast(bf16x8, *(const short8*)&Ab[aoffB + mi * 512]);
        }
        #pragma unroll
        for (int ni = 0; ni < 4; ++ni)
            bfr[ni] = *(const short8*)&Bc[boff + ni * 512];
        // stage tile kt+2 (A then B; issue order fixed by program order)
        if (MODE == 0) stage_a_f32(Afg, (float*)Au[wb], ks * GBK, K, wave, lane);
        else           stage_b16(Abg, (unsigned short*)Au[wb], ks * GBK, K, wave, lane);
        stage_b16(Bbase, Bl[wb], ks * GBK, K, wave, lane);
        __builtin_amdgcn_s_barrier();
        __builtin_amdgcn_s_setprio(1);
        #pragma unroll
        for (int mi = 0; mi < 4; ++mi)
            #pragma unroll
            for (int ni = 0; ni < 4; ++ni)
                acc[mi][ni] = __builtin_amdgcn_mfma_f32_16x16x32_bf16(
                    af0[mi], __builtin_bit_cast(bf16x8, bfr[ni]), acc[mi][ni], 0, 0, 0);
        __builtin_amdgcn_s_setprio(0);
        __builtin_amdgcn_s_barrier();

        // ================= phase 1: mi 4..7 =================
        bf16x8 af1[4];
        if (MODE == 0) {
            const float* Af = (const float*)Au[rb];
            #pragma unroll
            for (int mi = 0; mi < 4; ++mi) {
                f32x4 lo = *(const f32x4*)&Af[arow + (4 + mi) * 512 + sw0];
                f32x4 h4 = *(const f32x4*)&Af[arow + (4 + mi) * 512 + sw1];
                af1[mi] = cvt8(lo, h4);
            }
        } else {
            const unsigned short* Ab = (const unsigned short*)Au[rb];
            #pragma unroll
            for (int mi = 0; mi < 4; ++mi)
                af1[mi] = __builtin_bit_cast(bf16x8, *(const short8*)&Ab[aoffB + (4 + mi) * 512]);
        }
        // counted wait: drains tile kt+1's stages (issued last tile); tile
        // kt+2's stages (this tile's, 6 or 4 ops) stay in flight.
        if (MODE == 0) { asm volatile("s_waitcnt vmcnt(6)" ::: "memory"); }
        else           { asm volatile("s_waitcnt vmcnt(4)" ::: "memory"); }
        __builtin_amdgcn_s_barrier();
        __builtin_amdgcn_s_setprio(1);
        #pragma unroll
        for (int mi = 0; mi < 4; ++mi)
            #pragma unroll
            for (int ni = 0; ni < 4; ++ni)
                acc[4 + mi][ni] = __builtin_amdgcn_mfma_f32_16x16x32_bf16(
                    af1[mi], __builtin_bit_cast(bf16x8, bfr[ni]), acc[4 + mi][ni], 0, 0, 0);
        __builtin_amdgcn_s_setprio(0);
        __builtin_amdgcn_s_barrier();

        rb = (rb == 2) ? 0 : rb + 1;
    }

    __syncthreads();   // full drain (vmcnt+lgkmcnt) before LDS reuse

    // ---- epilogue: C/D layout col=lane&15, row=(lane>>4)*4+j ----
    const int cg = fr;
    const int rg = hi * 4;
    float* sblk = (float*)&Bl[0][0];
    if (MODE == 0) {
        if (tid < GBN) sblk[tid] = 0.f;
        __syncthreads();
    }
    float csum[4] = {};
    #pragma unroll
    for (int mi = 0; mi < 8; ++mi) {
        #pragma unroll
        for (int ni = 0; ni < 4; ++ni) {
            int col = bn * GBN + wc * 64 + ni * 16 + cg;
            float bv = bias[col];
            #pragma unroll
            for (int j = 0; j < 4; ++j) {
                int row = bm * GBM + wr * 128 + mi * 16 + rg + j;
                float v = acc[mi][ni][j] + bv;
                if (MODE == 0) {
                    ((unsigned short*)Cout)[(size_t)row * N + col] = f2bf(v);
                    csum[ni] += v * v;
                } else {
                    ((float*)Cout)[(size_t)row * N + col] = v;
                }
            }
        }
    }
    if (MODE == 0) {
        #pragma unroll
        for (int ni = 0; ni < 4; ++ni)
            atomicAdd(&sblk[wc * 64 + ni * 16 + cg], csum[ni]);
        __syncthreads();
        const int b = bm >> 4;   // 16 bm-tiles per batch
        if (tid < GBN) atomicAdd(&S[b * CC + bn * GBN + tid], sblk[tid]);
    }
}

// ---------------- per-row softmax over heads (bf16 w input) ----------------
// 4 waves/block, 8 rows/wave; per lane: channels c = q*512 + lane*8, q in {0,1};
// head h = q*8 + (lane>>3); 8-lane group reduce.
__global__ __launch_bounds__(256)
void k_row_softmax(const unsigned short* __restrict__ w16, const float* __restrict__ S,
                   const float* __restrict__ temp,
                   float* __restrict__ Pi, float* __restrict__ dotsU,
                   float* __restrict__ sumPi)
{
    __shared__ float dots_local[CC];
    __shared__ float sPi_local[HH];
    const int tid  = threadIdx.x;
    const int wave = tid >> 6;
    const int lane = tid & 63;
    const int bb   = blockIdx.x >> 7;
    const int tile = blockIdx.x & 127;

    for (int c = tid; c < CC; c += 256) dots_local[c] = 0.f;
    if (tid < HH) sPi_local[tid] = 0.f;
    __syncthreads();

    const int g3 = lane >> 3;
    const int li = lane & 7;

    float inv[2][8], tsc[2];
    #pragma unroll
    for (int q = 0; q < 2; ++q) {
        int c = q * 512 + lane * 8;
        const float4* sp = (const float4*)&S[bb * CC + c];
        float4 s0 = sp[0], s1 = sp[1];
        inv[q][0] = 1.f / fmaxf(s0.x, 1e-24f); inv[q][1] = 1.f / fmaxf(s0.y, 1e-24f);
        inv[q][2] = 1.f / fmaxf(s0.z, 1e-24f); inv[q][3] = 1.f / fmaxf(s0.w, 1e-24f);
        inv[q][4] = 1.f / fmaxf(s1.x, 1e-24f); inv[q][5] = 1.f / fmaxf(s1.y, 1e-24f);
        inv[q][6] = 1.f / fmaxf(s1.z, 1e-24f); inv[q][7] = 1.f / fmaxf(s1.w, 1e-24f);
        tsc[q] = temp[q * 8 + g3];
    }

    float dacc[2][8] = {};
    float sPiAcc[2] = {};

    for (int i = 0; i < 8; ++i) {
        int t = tile * 32 + wave * 8 + i;
        const unsigned short* row = w16 + ((size_t)bb * TT + t) * CC;
        float wf[2][8];
        float pq[2];
        #pragma unroll
        for (int q = 0; q < 2; ++q) {
            short8 v = *(const short8*)&row[q * 512 + lane * 8];
            float s = 0.f;
            #pragma unroll
            for (int j = 0; j < 8; ++j) {
                wf[q][j] = bf2f((unsigned short)v[j]);
                s += wf[q][j] * wf[q][j] * inv[q][j];
            }
            pq[q] = s;
        }
        #pragma unroll
        for (int off = 1; off < 8; off <<= 1) {
            pq[0] += __shfl_xor(pq[0], off);
            pq[1] += __shfl_xor(pq[1], off);
        }
        pq[0] *= tsc[0]; pq[1] *= tsc[1];
        float mx = fmaxf(pq[0], pq[1]);
        mx = fmaxf(mx, __shfl_xor(mx, 8));
        mx = fmaxf(mx, __shfl_xor(mx, 16));
        mx = fmaxf(mx, __shfl_xor(mx, 32));
        float e0 = __expf(pq[0] - mx), e1 = __expf(pq[1] - mx);
        float ss = e0 + e1;
        ss += __shfl_xor(ss, 8);
        ss += __shfl_xor(ss, 16);
        ss += __shfl_xor(ss, 32);
        float rs = 1.f / ss;
        float piv[2] = { e0 * rs, e1 * rs };
        #pragma unroll
        for (int q = 0; q < 2; ++q) {
            #pragma unroll
            for (int j = 0; j < 8; ++j)
                dacc[q][j] += piv[q] * wf[q][j] * wf[q][j];
            if (li == 0) {
                Pi[((size_t)(bb * HH + q * 8 + g3)) * TT + t] = piv[q];
                sPiAcc[q] += piv[q];
            }
        }
    }

    #pragma unroll
    for (int q = 0; q < 2; ++q) {
        int c = q * 512 + lane * 8;
        #pragma unroll
        for (int j = 0; j < 8; ++j)
            atomicAdd(&dots_local[c + j], dacc[q][j]);
        if (li == 0) atomicAdd(&sPi_local[q * 8 + g3], sPiAcc[q]);
    }
    __syncthreads();
    for (int c = tid; c < CC; c += 256) atomicAdd(&dotsU[bb * CC + c], dots_local[c]);
    if (tid < HH) atomicAdd(&sumPi[bb * HH + tid], sPi_local[tid]);
}

// ---------------- attnScale[b,c] = 1/(1 + dotsU/(sumPi+1e-8)) ----------------
__global__ void k_attnscale(const float* __restrict__ dotsU,
                            const float* __restrict__ sumPi,
                            float* __restrict__ attnScale) {
    int i = blockIdx.x * 256 + threadIdx.x;
    if (i >= BB * CC) return;
    int b = i >> 10;
    int h = (i >> 6) & 15;
    float sp = sumPi[b * HH + h] + 1e-8f;
    attnScale[i] = 1.f / (1.f + dotsU[i] / sp);
}

// ------- in-place: wy[b,t,c] = bf16( -(w*Pi[b,h,t]) * attnScale[b,c] ) -------
__global__ void k_make_y(unsigned short* __restrict__ wy, const float* __restrict__ Pi,
                         const float* __restrict__ attnScale)
{
    size_t i = (size_t)blockIdx.x * 256 + threadIdx.x;  // 8-elem groups
    size_t flat = i * 8;
    int c = (int)(flat & (CC - 1));
    size_t bt = flat >> 10;
    int t = (int)(bt & (TT - 1));
    int b = (int)(bt >> 12);
    int h = c >> 6;
    float pi = Pi[((size_t)(b * HH + h)) * TT + t];
    short8 wv = *(const short8*)&wy[flat];
    f32x4 a0 = *(const f32x4*)&attnScale[b * CC + c];
    f32x4 a1 = *(const f32x4*)&attnScale[b * CC + c + 4];
    short8 o;
    #pragma unroll
    for (int j = 0; j < 4; ++j) {
        o[j]     = (short)f2bf(-(bf2f((unsigned short)wv[j])     * pi) * a0[j]);
        o[4 + j] = (short)f2bf(-(bf2f((unsigned short)wv[4 + j]) * pi) * a1[j]);
    }
    *(short8*)&wy[flat] = o;
}

// ---------------- launch ----------------
extern "C" void kernel_launch(void* const* d_in, const int* in_sizes, int n_in,
                              void* d_out, int out_size, void* d_ws, size_t ws_size,
                              hipStream_t stream) {
    const float* x      = (const float*)d_in[0];
    const float* W_attn = (const float*)d_in[1];
    const float* b_attn = (const float*)d_in[2];
    const float* W_proj = (const float*)d_in[3];
    const float* b_proj = (const float*)d_in[4];
    const float* temp   = (const float*)d_in[5];

    char* ws = (char*)d_ws;
    unsigned short* w16  = (unsigned short*)(ws);             // 33554432 B (w, then y in-place)
    unsigned short* Wa16 = (unsigned short*)(ws + 33554432);  // 2097152 B
    unsigned short* Wp16 = (unsigned short*)(ws + 35651584);  // 2097152 B
    float* Pi        = (float*)(ws + 37748736);  // 1048576 B
    float* S         = (float*)(ws + 38797312);  // 16384 B
    float* dotsU     = (float*)(ws + 38813696);  // 16384 B
    float* sumPi     = (float*)(ws + 38830080);  // 256 B
    float* attnScale = (float*)(ws + 38830336);  // 16384 B

    // weights -> bf16
    k_f32_to_bf16<<<dim3(1024), dim3(256), 0, stream>>>(W_attn, Wa16, 262144);
    k_f32_to_bf16<<<dim3(1024), dim3(256), 0, stream>>>(W_proj, Wp16, 262144);

    // zero accumulators (S, dotsU, sumPi contiguous)
    hipMemsetAsync(S, 0, 16384 + 16384 + 256, stream);

    // GEMM1: w16 = bf16(x @ Wa^T + b_attn); S[b,c] = sum_t w^2 (A staged fp32)
    k_gemm256<0><<<dim3(256), dim3(512), 0, stream>>>(
        x, Wa16, b_attn, w16, S, BB * TT, CC, CC);

    // head-softmax per token: Pi, dotsU, sumPi
    k_row_softmax<<<dim3(512), dim3(256), 0, stream>>>(w16, S, temp, Pi, dotsU, sumPi);

    // attn scale
    k_attnscale<<<dim3(16), dim3(256), 0, stream>>>(dotsU, sumPi, attnScale);

    // y = -(w*Pi)*attnScale, in place on w16  (16.78M elems / 8 per thread / 256)
    k_make_y<<<dim3(8192), dim3(256), 0, stream>>>(w16, Pi, attnScale);

    // GEMM2: out = y @ Wp^T + b_proj
    k_gemm256<1><<<dim3(256), dim3(512), 0, stream>>>(
        w16, Wp16, b_proj, d_out, nullptr, BB * TT, CC, CC);
}

// Round 8
// 142.825 us; speedup vs baseline: 1.3852x; 1.0546x over previous
//
#include <hip/hip_runtime.h>
#include <hip/hip_bf16.h>

// Problem constants: B=4, T=4096, C=1024, H=16, D=64
#define BB 4
#define TT 4096
#define CC 1024
#define HH 16
#define DD 64

typedef __attribute__((ext_vector_type(8))) short short8;
typedef __attribute__((ext_vector_type(8))) __bf16 bf16x8;
typedef __attribute__((ext_vector_type(4))) float f32x4;

static __device__ __forceinline__ unsigned short f2bf(float f) {
    unsigned int u = __builtin_bit_cast(unsigned int, f);
    unsigned int r = (u + 0x7FFFu + ((u >> 16) & 1u)) >> 16;
    return (unsigned short)r;
}
static __device__ __forceinline__ float bf2f(unsigned short h) {
    return __builtin_bit_cast(float, ((unsigned int)h) << 16);
}

// ---------------- fp32 -> bf16 conversion ----------------
__global__ void k_f32_to_bf16(const float* __restrict__ src,
                              unsigned short* __restrict__ dst, int n4) {
    int i = blockIdx.x * 256 + threadIdx.x;
    if (i >= n4) return;
    float4 v = ((const float4*)src)[i];
    ushort4 o;
    o.x = f2bf(v.x); o.y = f2bf(v.y); o.z = f2bf(v.z); o.w = f2bf(v.w);
    ((ushort4*)dst)[i] = o;
}

// ================= 256x256 phase-pipelined bf16 GEMM (round-4 structure) =================
// C[m,n] = sum_k A[m,k]*B[n,k] + bias[n];  A: MxK, B: NxK row-major bf16.
// 8 waves (2M x 4N), per-wave output 128x64. BK=32.
// 4-buffer LDS rotation (4 x 32KB): compute kt from buf[kt&3], stage kt+3
// into buf[(kt+3)&3] (its readers finished at kt-1 -> race-free).
// 2 phases per K-tile; one counted vmcnt(8) per K-tile (3 tiles in flight).
// LDS rows 64B; rotate-swizzle slot=(hi+(r>>1))&3 (2-way bank alias = free);
// staging writes linear LDS dest with inverse-permuted global src (rule #21).
// MODE 0: C written bf16 + fused column sum-of-squares S. MODE 1: C fp32.
#define GBM 256
#define GBN 256
#define GBK 32

static __device__ __forceinline__ void stage_tile32(
    const unsigned short* __restrict__ Gbase, unsigned short* lbase,
    int k0, int K, int wave, int lane)
{
    #pragma unroll
    for (int q = 0; q < 2; ++q) {
        int c = (wave * 2 + q) * 64 + lane;
        int r = c >> 2;
        int j = c & 3;
        int srcj = (j - (r >> 1)) & 3;
        const unsigned short* g = Gbase + (size_t)r * K + k0 + srcj * 8;
        __builtin_amdgcn_global_load_lds(
            (const __attribute__((address_space(1))) void*)g,
            (__attribute__((address_space(3))) void*)(lbase + (wave * 2 + q) * 512),
            16, 0, 0);
    }
}

template<int MODE>
__global__ __launch_bounds__(512, 2)
void k_gemm256(const unsigned short* __restrict__ A,
               const unsigned short* __restrict__ B,
               const float* __restrict__ bias,
               void* __restrict__ Cout,
               float* __restrict__ S,
               int M, int N, int K)
{
    // per buffer: A tile [256][32] = 8192 ushorts, then B tile 8192 ushorts
    __shared__ unsigned short lds[4][16384];   // 128 KB
    const int tid  = threadIdx.x;
    const int wave = tid >> 6;
    const int lane = tid & 63;
    const int wr = wave >> 2;   // 0..1
    const int wc = wave & 3;    // 0..3
    const int fr = lane & 15;
    const int hi = lane >> 4;   // 0..3

    // XCD-aware bijective swizzle (256 blocks, 8 XCDs, chunk=32, bn fastest)
    const int wg  = blockIdx.x;
    const int swz = (wg & 7) * 32 + (wg >> 3);
    const int bn  = swz & 3;
    const int bm  = swz >> 2;

    const unsigned short* Abase = A + (size_t)(bm * GBM) * K;
    const unsigned short* Bbase = B + (size_t)(bn * GBN) * K;

    const int nt = K / GBK;   // 32

    // per-lane constant read offsets (ushort idx):
    const int sl   = (hi + (fr >> 1)) & 3;
    const int aoff = (wr * 128 + fr) * 32 + sl * 8;          // + mi*512
    const int boff = 8192 + (wc * 64 + fr) * 32 + sl * 8;    // + ni*512

    f32x4 acc[8][4] = {};

    // ---- prologue: stage tiles 0,1,2 ----
    stage_tile32(Abase, lds[0],        0,       K, wave, lane);
    stage_tile32(Bbase, lds[0] + 8192, 0,       K, wave, lane);
    stage_tile32(Abase, lds[1],        GBK,     K, wave, lane);
    stage_tile32(Bbase, lds[1] + 8192, GBK,     K, wave, lane);
    stage_tile32(Abase, lds[2],        2 * GBK, K, wave, lane);
    stage_tile32(Bbase, lds[2] + 8192, 2 * GBK, K, wave, lane);
    asm volatile("s_waitcnt vmcnt(8)" ::: "memory");   // tile 0 landed
    __builtin_amdgcn_s_barrier();

    for (int kt = 0; kt < nt; ++kt) {
        const unsigned short* buf = lds[kt & 3];
        unsigned short* sbuf = lds[(kt + 3) & 3];
        int k3 = kt + 3; if (k3 >= nt) k3 = nt - 1;

        // ================= phase 0: mi 0..3 =================
        short8 af0[4], bf0[4];
        #pragma unroll
        for (int i = 0; i < 4; ++i) af0[i] = *(const short8*)&buf[aoff + i * 512];
        #pragma unroll
        for (int i = 0; i < 4; ++i) bf0[i] = *(const short8*)&buf[boff + i * 512];
        stage_tile32(Abase, sbuf, k3 * GBK, K, wave, lane);
        __builtin_amdgcn_s_barrier();
        asm volatile("s_waitcnt lgkmcnt(0)" ::: "memory");
        __builtin_amdgcn_s_setprio(1);
        #pragma unroll
        for (int mi = 0; mi < 4; ++mi)
            #pragma unroll
            for (int ni = 0; ni < 4; ++ni)
                acc[mi][ni] = __builtin_amdgcn_mfma_f32_16x16x32_bf16(
                    __builtin_bit_cast(bf16x8, af0[mi]),
                    __builtin_bit_cast(bf16x8, bf0[ni]),
                    acc[mi][ni], 0, 0, 0);
        __builtin_amdgcn_s_setprio(0);
        __builtin_amdgcn_s_barrier();

        // ================= phase 1: mi 4..7 =================
        short8 af1[4], bf1[4];
        #pragma unroll
        for (int i = 0; i < 4; ++i) af1[i] = *(const short8*)&buf[aoff + (4 + i) * 512];
        #pragma unroll
        for (int i = 0; i < 4; ++i) bf1[i] = *(const short8*)&buf[boff + i * 512];
        stage_tile32(Bbase, sbuf + 8192, k3 * GBK, K, wave, lane);
        // counted wait, once per K-tile: tile kt+1 fully landed
        // (after it: tiles kt+2,kt+3 = 8 loads/thread remain in flight)
        asm volatile("s_waitcnt vmcnt(8)" ::: "memory");
        __builtin_amdgcn_s_barrier();
        asm volatile("s_waitcnt lgkmcnt(0)" ::: "memory");
        __builtin_amdgcn_s_setprio(1);
        #pragma unroll
        for (int mi = 0; mi < 4; ++mi)
            #pragma unroll
            for (int ni = 0; ni < 4; ++ni)
                acc[4 + mi][ni] = __builtin_amdgcn_mfma_f32_16x16x32_bf16(
                    __builtin_bit_cast(bf16x8, af1[mi]),
                    __builtin_bit_cast(bf16x8, bf1[ni]),
                    acc[4 + mi][ni], 0, 0, 0);
        __builtin_amdgcn_s_setprio(0);
        __builtin_amdgcn_s_barrier();
    }

    __syncthreads();   // full drain (vmcnt+lgkmcnt) before LDS reuse

    // ---- epilogue: C/D layout col=lane&15, row=(lane>>4)*4+j ----
    const int cg = fr;
    const int rg = hi * 4;
    float* sblk = (float*)&lds[0][0];
    if (MODE == 0) {
        if (tid < GBN) sblk[tid] = 0.f;
        __syncthreads();
    }
    float csum[4] = {};
    #pragma unroll
    for (int mi = 0; mi < 8; ++mi) {
        #pragma unroll
        for (int ni = 0; ni < 4; ++ni) {
            int col = bn * GBN + wc * 64 + ni * 16 + cg;
            float bv = bias[col];
            #pragma unroll
            for (int j = 0; j < 4; ++j) {
                int row = bm * GBM + wr * 128 + mi * 16 + rg + j;
                float v = acc[mi][ni][j] + bv;
                if (MODE == 0) {
                    ((unsigned short*)Cout)[(size_t)row * N + col] = f2bf(v);
                    csum[ni] += v * v;
                } else {
                    ((float*)Cout)[(size_t)row * N + col] = v;
                }
            }
        }
    }
    if (MODE == 0) {
        #pragma unroll
        for (int ni = 0; ni < 4; ++ni)
            atomicAdd(&sblk[wc * 64 + ni * 16 + cg], csum[ni]);
        __syncthreads();
        const int b = bm >> 4;   // 16 bm-tiles per batch (4096/256)
        if (tid < GBN) atomicAdd(&S[b * CC + bn * GBN + tid], sblk[tid]);
    }
}

// ---------------- per-row softmax over heads (bf16 w input) ----------------
// 4 waves/block, 8 rows/wave; per lane: channels c = q*512 + lane*8, q in {0,1};
// head h = q*8 + (lane>>3); 8-lane group reduce.
__global__ __launch_bounds__(256)
void k_row_softmax(const unsigned short* __restrict__ w16, const float* __restrict__ S,
                   const float* __restrict__ temp,
                   float* __restrict__ Pi, float* __restrict__ dotsU,
                   float* __restrict__ sumPi)
{
    __shared__ float dots_local[CC];
    __shared__ float sPi_local[HH];
    const int tid  = threadIdx.x;
    const int wave = tid >> 6;
    const int lane = tid & 63;
    const int bb   = blockIdx.x >> 7;
    const int tile = blockIdx.x & 127;

    for (int c = tid; c < CC; c += 256) dots_local[c] = 0.f;
    if (tid < HH) sPi_local[tid] = 0.f;
    __syncthreads();

    const int g3 = lane >> 3;
    const int li = lane & 7;

    float inv[2][8], tsc[2];
    #pragma unroll
    for (int q = 0; q < 2; ++q) {
        int c = q * 512 + lane * 8;
        const float4* sp = (const float4*)&S[bb * CC + c];
        float4 s0 = sp[0], s1 = sp[1];
        inv[q][0] = 1.f / fmaxf(s0.x, 1e-24f); inv[q][1] = 1.f / fmaxf(s0.y, 1e-24f);
        inv[q][2] = 1.f / fmaxf(s0.z, 1e-24f); inv[q][3] = 1.f / fmaxf(s0.w, 1e-24f);
        inv[q][4] = 1.f / fmaxf(s1.x, 1e-24f); inv[q][5] = 1.f / fmaxf(s1.y, 1e-24f);
        inv[q][6] = 1.f / fmaxf(s1.z, 1e-24f); inv[q][7] = 1.f / fmaxf(s1.w, 1e-24f);
        tsc[q] = temp[q * 8 + g3];
    }

    float dacc[2][8] = {};
    float sPiAcc[2] = {};

    for (int i = 0; i < 8; ++i) {
        int t = tile * 32 + wave * 8 + i;
        const unsigned short* row = w16 + ((size_t)bb * TT + t) * CC;
        float wf[2][8];
        float pq[2];
        #pragma unroll
        for (int q = 0; q < 2; ++q) {
            short8 v = *(const short8*)&row[q * 512 + lane * 8];
            float s = 0.f;
            #pragma unroll
            for (int j = 0; j < 8; ++j) {
                wf[q][j] = bf2f((unsigned short)v[j]);
                s += wf[q][j] * wf[q][j] * inv[q][j];
            }
            pq[q] = s;
        }
        #pragma unroll
        for (int off = 1; off < 8; off <<= 1) {
            pq[0] += __shfl_xor(pq[0], off);
            pq[1] += __shfl_xor(pq[1], off);
        }
        pq[0] *= tsc[0]; pq[1] *= tsc[1];
        float mx = fmaxf(pq[0], pq[1]);
        mx = fmaxf(mx, __shfl_xor(mx, 8));
        mx = fmaxf(mx, __shfl_xor(mx, 16));
        mx = fmaxf(mx, __shfl_xor(mx, 32));
        float e0 = __expf(pq[0] - mx), e1 = __expf(pq[1] - mx);
        float ss = e0 + e1;
        ss += __shfl_xor(ss, 8);
        ss += __shfl_xor(ss, 16);
        ss += __shfl_xor(ss, 32);
        float rs = 1.f / ss;
        float piv[2] = { e0 * rs, e1 * rs };
        #pragma unroll
        for (int q = 0; q < 2; ++q) {
            #pragma unroll
            for (int j = 0; j < 8; ++j)
                dacc[q][j] += piv[q] * wf[q][j] * wf[q][j];
            if (li == 0) {
                Pi[((size_t)(bb * HH + q * 8 + g3)) * TT + t] = piv[q];
                sPiAcc[q] += piv[q];
            }
        }
    }

    #pragma unroll
    for (int q = 0; q < 2; ++q) {
        int c = q * 512 + lane * 8;
        #pragma unroll
        for (int j = 0; j < 8; ++j)
            atomicAdd(&dots_local[c + j], dacc[q][j]);
        if (li == 0) atomicAdd(&sPi_local[q * 8 + g3], sPiAcc[q]);
    }
    __syncthreads();
    for (int c = tid; c < CC; c += 256) atomicAdd(&dotsU[bb * CC + c], dots_local[c]);
    if (tid < HH) atomicAdd(&sumPi[bb * HH + tid], sPi_local[tid]);
}

// ---------------- attnScale[b,c] = 1/(1 + dotsU/(sumPi+1e-8)) ----------------
__global__ void k_attnscale(const float* __restrict__ dotsU,
                            const float* __restrict__ sumPi,
                            float* __restrict__ attnScale) {
    int i = blockIdx.x * 256 + threadIdx.x;
    if (i >= BB * CC) return;
    int b = i >> 10;
    int h = (i >> 6) & 15;
    float sp = sumPi[b * HH + h] + 1e-8f;
    attnScale[i] = 1.f / (1.f + dotsU[i] / sp);
}

// ------- in-place: wy[b,t,c] = bf16( -(w*Pi[b,h,t]) * attnScale[b,c] ) -------
__global__ void k_make_y(unsigned short* __restrict__ wy, const float* __restrict__ Pi,
                         const float* __restrict__ attnScale)
{
    size_t i = (size_t)blockIdx.x * 256 + threadIdx.x;  // 8-elem groups
    size_t flat = i * 8;
    int c = (int)(flat & (CC - 1));
    size_t bt = flat >> 10;
    int t = (int)(bt & (TT - 1));
    int b = (int)(bt >> 12);
    int h = c >> 6;
    float pi = Pi[((size_t)(b * HH + h)) * TT + t];
    short8 wv = *(const short8*)&wy[flat];
    f32x4 a0 = *(const f32x4*)&attnScale[b * CC + c];
    f32x4 a1 = *(const f32x4*)&attnScale[b * CC + c + 4];
    short8 o;
    #pragma unroll
    for (int j = 0; j < 4; ++j) {
        o[j]     = (short)f2bf(-(bf2f((unsigned short)wv[j])     * pi) * a0[j]);
        o[4 + j] = (short)f2bf(-(bf2f((unsigned short)wv[4 + j]) * pi) * a1[j]);
    }
    *(short8*)&wy[flat] = o;
}

// ---------------- launch ----------------
extern "C" void kernel_launch(void* const* d_in, const int* in_sizes, int n_in,
                              void* d_out, int out_size, void* d_ws, size_t ws_size,
                              hipStream_t stream) {
    const float* x      = (const float*)d_in[0];
    const float* W_attn = (const float*)d_in[1];
    const float* b_attn = (const float*)d_in[2];
    const float* W_proj = (const float*)d_in[3];
    const float* b_proj = (const float*)d_in[4];
    const float* temp   = (const float*)d_in[5];

    // xb (x as bf16, 32MB) lives in the FIRST HALF of d_out: it is fully dead
    // before GEMM2 starts writing fp32 output over d_out. All other scratch in ws.
    unsigned short* xb = (unsigned short*)d_out;

    char* ws = (char*)d_ws;
    unsigned short* w16  = (unsigned short*)(ws);             // 33554432 B (w, then y in-place)
    unsigned short* Wa16 = (unsigned short*)(ws + 33554432);  // 2097152 B
    unsigned short* Wp16 = (unsigned short*)(ws + 35651584);  // 2097152 B
    float* Pi        = (float*)(ws + 37748736);  // 1048576 B
    float* S         = (float*)(ws + 38797312);  // 16384 B
    float* dotsU     = (float*)(ws + 38813696);  // 16384 B
    float* sumPi     = (float*)(ws + 38830080);  // 256 B
    float* attnScale = (float*)(ws + 38830336);  // 16384 B

    // conversions
    k_f32_to_bf16<<<dim3(16384), dim3(256), 0, stream>>>(x, xb, 4194304);
    k_f32_to_bf16<<<dim3(1024), dim3(256), 0, stream>>>(W_attn, Wa16, 262144);
    k_f32_to_bf16<<<dim3(1024), dim3(256), 0, stream>>>(W_proj, Wp16, 262144);

    // zero accumulators (S, dotsU, sumPi contiguous)
    hipMemsetAsync(S, 0, 16384 + 16384 + 256, stream);

    // GEMM1: w16 = bf16(xb @ Wa^T + b_attn); fused S[b,c] = sum_t w^2
    k_gemm256<0><<<dim3(256), dim3(512), 0, stream>>>(
        xb, Wa16, b_attn, w16, S, BB * TT, CC, CC);

    // head-softmax per token: Pi, dotsU, sumPi
    k_row_softmax<<<dim3(512), dim3(256), 0, stream>>>(w16, S, temp, Pi, dotsU, sumPi);

    // attn scale
    k_attnscale<<<dim3(16), dim3(256), 0, stream>>>(dotsU, sumPi, attnScale);

    // y = -(w*Pi)*attnScale, in place on w16 (16.78M elems / 8 per thread / 256)
    k_make_y<<<dim3(8192), dim3(256), 0, stream>>>(w16, Pi, attnScale);

    // GEMM2: out = y @ Wp^T + b_proj (fp32, overwrites xb region of d_out)
    k_gemm256<1><<<dim3(256), dim3(512), 0, stream>>>(
        w16, Wp16, b_proj, d_out, nullptr, BB * TT, CC, CC);
}

// Round 10
// 131.003 us; speedup vs baseline: 1.5102x; 1.0902x over previous
//
#include <hip/hip_runtime.h>
#include <hip/hip_bf16.h>

// Problem constants: B=4, T=4096, C=1024, H=16, D=64
#define BB 4
#define TT 4096
#define CC 1024
#define HH 16
#define DD 64

typedef __attribute__((ext_vector_type(8))) short short8;
typedef __attribute__((ext_vector_type(8))) __bf16 bf16x8;
typedef __attribute__((ext_vector_type(4))) float f32x4;

static __device__ __forceinline__ unsigned short f2bf(float f) {
    unsigned int u = __builtin_bit_cast(unsigned int, f);
    unsigned int r = (u + 0x7FFFu + ((u >> 16) & 1u)) >> 16;
    return (unsigned short)r;
}
static __device__ __forceinline__ float bf2f(unsigned short h) {
    return __builtin_bit_cast(float, ((unsigned int)h) << 16);
}

// ---------------- fp32 -> bf16 conversion ----------------
__global__ void k_f32_to_bf16(const float* __restrict__ src,
                              unsigned short* __restrict__ dst, int n4) {
    int i = blockIdx.x * 256 + threadIdx.x;
    if (i >= n4) return;
    float4 v = ((const float4*)src)[i];
    ushort4 o;
    o.x = f2bf(v.x); o.y = f2bf(v.y); o.z = f2bf(v.z); o.w = f2bf(v.w);
    ((ushort4*)dst)[i] = o;
}

// ================= 256x256 phase-pipelined bf16 GEMM (round-4 structure) =================
// C[m,n] = sum_k A[m,k]*B[n,k] + bias[n];  A: MxK, B: NxK row-major bf16.
// 8 waves (2M x 4N), per-wave output 128x64. BK=32.
// 4-buffer LDS rotation (4 x 32KB): compute kt from buf[kt&3], stage kt+3
// into buf[(kt+3)&3] (its readers finished at kt-1 -> race-free).
// 2 phases per K-tile; one counted vmcnt(8) per K-tile (3 tiles in flight).
// B fragments read once per K-tile, reused in registers for phase 1.
// MODE 0: C written bf16 + fused column sum-of-squares S (B shared).
// MODE 1: C fp32, B is PER-BATCH (Wp' holds attnScale fold): Bbase += b*N*K.
#define GBM 256
#define GBN 256
#define GBK 32

static __device__ __forceinline__ void stage_tile32(
    const unsigned short* __restrict__ Gbase, unsigned short* lbase,
    int k0, int K, int wave, int lane)
{
    #pragma unroll
    for (int q = 0; q < 2; ++q) {
        int c = (wave * 2 + q) * 64 + lane;
        int r = c >> 2;
        int j = c & 3;
        int srcj = (j - (r >> 1)) & 3;
        const unsigned short* g = Gbase + (size_t)r * K + k0 + srcj * 8;
        __builtin_amdgcn_global_load_lds(
            (const __attribute__((address_space(1))) void*)g,
            (__attribute__((address_space(3))) void*)(lbase + (wave * 2 + q) * 512),
            16, 0, 0);
    }
}

template<int MODE>
__global__ __launch_bounds__(512, 2)
void k_gemm256(const unsigned short* __restrict__ A,
               const unsigned short* __restrict__ B,
               const float* __restrict__ bias,
               void* __restrict__ Cout,
               float* __restrict__ S,
               int M, int N, int K)
{
    // per buffer: A tile [256][32] = 8192 ushorts, then B tile 8192 ushorts
    __shared__ unsigned short lds[4][16384];   // 128 KB
    const int tid  = threadIdx.x;
    const int wave = tid >> 6;
    const int lane = tid & 63;
    const int wr = wave >> 2;   // 0..1
    const int wc = wave & 3;    // 0..3
    const int fr = lane & 15;
    const int hi = lane >> 4;   // 0..3

    // XCD-aware bijective swizzle (256 blocks, 8 XCDs, chunk=32, bn fastest)
    const int wg  = blockIdx.x;
    const int swz = (wg & 7) * 32 + (wg >> 3);
    const int bn  = swz & 3;
    const int bm  = swz >> 2;
    const int b   = bm >> 4;    // batch (16 bm-tiles per batch)

    const unsigned short* Abase = A + (size_t)(bm * GBM) * K;
    const unsigned short* Bbase = B +
        ((size_t)((MODE == 1 ? b * N : 0) + bn * GBN)) * K;

    const int nt = K / GBK;   // 32

    // per-lane constant read offsets (ushort idx):
    const int sl   = (hi + (fr >> 1)) & 3;
    const int aoff = (wr * 128 + fr) * 32 + sl * 8;          // + mi*512
    const int boff = 8192 + (wc * 64 + fr) * 32 + sl * 8;    // + ni*512

    f32x4 acc[8][4] = {};

    // ---- prologue: stage tiles 0,1,2 ----
    stage_tile32(Abase, lds[0],        0,       K, wave, lane);
    stage_tile32(Bbase, lds[0] + 8192, 0,       K, wave, lane);
    stage_tile32(Abase, lds[1],        GBK,     K, wave, lane);
    stage_tile32(Bbase, lds[1] + 8192, GBK,     K, wave, lane);
    stage_tile32(Abase, lds[2],        2 * GBK, K, wave, lane);
    stage_tile32(Bbase, lds[2] + 8192, 2 * GBK, K, wave, lane);
    asm volatile("s_waitcnt vmcnt(8)" ::: "memory");   // tile 0 landed
    __builtin_amdgcn_s_barrier();

    for (int kt = 0; kt < nt; ++kt) {
        const unsigned short* buf = lds[kt & 3];
        unsigned short* sbuf = lds[(kt + 3) & 3];
        int k3 = kt + 3; if (k3 >= nt) k3 = nt - 1;

        // ================= phase 0: mi 0..3 =================
        short8 af0[4], bf0[4];
        #pragma unroll
        for (int i = 0; i < 4; ++i) af0[i] = *(const short8*)&buf[aoff + i * 512];
        #pragma unroll
        for (int i = 0; i < 4; ++i) bf0[i] = *(const short8*)&buf[boff + i * 512];
        stage_tile32(Abase, sbuf, k3 * GBK, K, wave, lane);
        __builtin_amdgcn_s_barrier();
        asm volatile("s_waitcnt lgkmcnt(0)" ::: "memory");
        __builtin_amdgcn_s_setprio(1);
        #pragma unroll
        for (int mi = 0; mi < 4; ++mi)
            #pragma unroll
            for (int ni = 0; ni < 4; ++ni)
                acc[mi][ni] = __builtin_amdgcn_mfma_f32_16x16x32_bf16(
                    __builtin_bit_cast(bf16x8, af0[mi]),
                    __builtin_bit_cast(bf16x8, bf0[ni]),
                    acc[mi][ni], 0, 0, 0);
        __builtin_amdgcn_s_setprio(0);
        __builtin_amdgcn_s_barrier();

        // ================= phase 1: mi 4..7 (B frags reused from phase 0) ======
        short8 af1[4];
        #pragma unroll
        for (int i = 0; i < 4; ++i) af1[i] = *(const short8*)&buf[aoff + (4 + i) * 512];
        stage_tile32(Bbase, sbuf + 8192, k3 * GBK, K, wave, lane);
        // counted wait, once per K-tile: tile kt+1 fully landed
        // (after it: tiles kt+2,kt+3 = 8 loads/thread remain in flight)
        asm volatile("s_waitcnt vmcnt(8)" ::: "memory");
        __builtin_amdgcn_s_barrier();
        asm volatile("s_waitcnt lgkmcnt(0)" ::: "memory");
        __builtin_amdgcn_s_setprio(1);
        #pragma unroll
        for (int mi = 0; mi < 4; ++mi)
            #pragma unroll
            for (int ni = 0; ni < 4; ++ni)
                acc[4 + mi][ni] = __builtin_amdgcn_mfma_f32_16x16x32_bf16(
                    __builtin_bit_cast(bf16x8, af1[mi]),
                    __builtin_bit_cast(bf16x8, bf0[ni]),
                    acc[4 + mi][ni], 0, 0, 0);
        __builtin_amdgcn_s_setprio(0);
        __builtin_amdgcn_s_barrier();
    }

    __syncthreads();   // full drain (vmcnt+lgkmcnt) before LDS reuse

    // ---- epilogue: C/D layout col=lane&15, row=(lane>>4)*4+j ----
    const int cg = fr;
    const int rg = hi * 4;
    float* sblk = (float*)&lds[0][0];
    if (MODE == 0) {
        if (tid < GBN) sblk[tid] = 0.f;
        __syncthreads();
    }
    float csum[4] = {};
    #pragma unroll
    for (int mi = 0; mi < 8; ++mi) {
        #pragma unroll
        for (int ni = 0; ni < 4; ++ni) {
            int col = bn * GBN + wc * 64 + ni * 16 + cg;
            float bv = bias[col];
            #pragma unroll
            for (int j = 0; j < 4; ++j) {
                int row = bm * GBM + wr * 128 + mi * 16 + rg + j;
                float v = acc[mi][ni][j] + bv;
                if (MODE == 0) {
                    ((unsigned short*)Cout)[(size_t)row * N + col] = f2bf(v);
                    csum[ni] += v * v;
                } else {
                    ((float*)Cout)[(size_t)row * N + col] = v;
                }
            }
        }
    }
    if (MODE == 0) {
        #pragma unroll
        for (int ni = 0; ni < 4; ++ni)
            atomicAdd(&sblk[wc * 64 + ni * 16 + cg], csum[ni]);
        __syncthreads();
        if (tid < GBN) atomicAdd(&S[b * CC + bn * GBN + tid], sblk[tid]);
    }
}

// ------- per-row softmax over heads + IN-PLACE y = bf16(-(w*Pi)) -------
// 4 waves/block, 8 rows/wave; per lane: channels c = q*512 + lane*8, q in {0,1};
// head h = q*8 + (lane>>3); 8-lane group reduce. Also accumulates dotsU, sumPi.
__global__ __launch_bounds__(256)
void k_row_softmax(unsigned short* __restrict__ w16, const float* __restrict__ S,
                   const float* __restrict__ temp,
                   float* __restrict__ dotsU, float* __restrict__ sumPi)
{
    __shared__ float dots_local[CC];
    __shared__ float sPi_local[HH];
    const int tid  = threadIdx.x;
    const int wave = tid >> 6;
    const int lane = tid & 63;
    const int bb   = blockIdx.x >> 7;
    const int tile = blockIdx.x & 127;

    for (int c = tid; c < CC; c += 256) dots_local[c] = 0.f;
    if (tid < HH) sPi_local[tid] = 0.f;
    __syncthreads();

    const int g3 = lane >> 3;
    const int li = lane & 7;

    float inv[2][8], tsc[2];
    #pragma unroll
    for (int q = 0; q < 2; ++q) {
        int c = q * 512 + lane * 8;
        const float4* sp = (const float4*)&S[bb * CC + c];
        float4 s0 = sp[0], s1 = sp[1];
        inv[q][0] = 1.f / fmaxf(s0.x, 1e-24f); inv[q][1] = 1.f / fmaxf(s0.y, 1e-24f);
        inv[q][2] = 1.f / fmaxf(s0.z, 1e-24f); inv[q][3] = 1.f / fmaxf(s0.w, 1e-24f);
        inv[q][4] = 1.f / fmaxf(s1.x, 1e-24f); inv[q][5] = 1.f / fmaxf(s1.y, 1e-24f);
        inv[q][6] = 1.f / fmaxf(s1.z, 1e-24f); inv[q][7] = 1.f / fmaxf(s1.w, 1e-24f);
        tsc[q] = temp[q * 8 + g3];
    }

    float dacc[2][8] = {};
    float sPiAcc[2] = {};

    for (int i = 0; i < 8; ++i) {
        int t = tile * 32 + wave * 8 + i;
        unsigned short* row = w16 + ((size_t)bb * TT + t) * CC;
        float wf[2][8];
        float pq[2];
        #pragma unroll
        for (int q = 0; q < 2; ++q) {
            short8 v = *(const short8*)&row[q * 512 + lane * 8];
            float s = 0.f;
            #pragma unroll
            for (int j = 0; j < 8; ++j) {
                wf[q][j] = bf2f((unsigned short)v[j]);
                s += wf[q][j] * wf[q][j] * inv[q][j];
            }
            pq[q] = s;
        }
        #pragma unroll
        for (int off = 1; off < 8; off <<= 1) {
            pq[0] += __shfl_xor(pq[0], off);
            pq[1] += __shfl_xor(pq[1], off);
        }
        pq[0] *= tsc[0]; pq[1] *= tsc[1];
        float mx = fmaxf(pq[0], pq[1]);
        mx = fmaxf(mx, __shfl_xor(mx, 8));
        mx = fmaxf(mx, __shfl_xor(mx, 16));
        mx = fmaxf(mx, __shfl_xor(mx, 32));
        float e0 = __expf(pq[0] - mx), e1 = __expf(pq[1] - mx);
        float ss = e0 + e1;
        ss += __shfl_xor(ss, 8);
        ss += __shfl_xor(ss, 16);
        ss += __shfl_xor(ss, 32);
        float rs = 1.f / ss;
        float piv[2] = { e0 * rs, e1 * rs };
        #pragma unroll
        for (int q = 0; q < 2; ++q) {
            short8 yo;
            #pragma unroll
            for (int j = 0; j < 8; ++j) {
                dacc[q][j] += piv[q] * wf[q][j] * wf[q][j];
                yo[j] = (short)f2bf(-wf[q][j] * piv[q]);
            }
            *(short8*)&row[q * 512 + lane * 8] = yo;   // in-place y = -(w*Pi)
            if (li == 0) sPiAcc[q] += piv[q];
        }
    }

    #pragma unroll
    for (int q = 0; q < 2; ++q) {
        int c = q * 512 + lane * 8;
        #pragma unroll
        for (int j = 0; j < 8; ++j)
            atomicAdd(&dots_local[c + j], dacc[q][j]);
        if (li == 0) atomicAdd(&sPi_local[q * 8 + g3], sPiAcc[q]);
    }
    __syncthreads();
    for (int c = tid; c < CC; c += 256) atomicAdd(&dotsU[bb * CC + c], dots_local[c]);
    if (tid < HH) atomicAdd(&sumPi[bb * HH + tid], sPi_local[tid]);
}

// -- Wp'[b,n,c] = bf16( Wp[n,c] * (+1/(1 + dotsU[b,c]/(sumPi[b,h]+1e-8))) ) --
// (sign: y already carries the minus; folding -attn here would double-negate)
__global__ void k_scale_wproj(const float* __restrict__ Wp,
                              const float* __restrict__ dotsU,
                              const float* __restrict__ sumPi,
                              unsigned short* __restrict__ out)
{
    int i = blockIdx.x * 256 + threadIdx.x;   // 1,048,576 groups of 4
    int bq  = i >> 18;                        // batch
    int rem = i & 262143;
    int n   = rem >> 8;
    int cg  = (rem & 255) * 4;
    float4 wv = *(const float4*)&Wp[n * CC + cg];
    float4 du = *(const float4*)&dotsU[bq * CC + cg];
    float sp = sumPi[bq * HH + (cg >> 6)] + 1e-8f;
    float a0 = 1.f / (1.f + du.x / sp);
    float a1 = 1.f / (1.f + du.y / sp);
    float a2 = 1.f / (1.f + du.z / sp);
    float a3 = 1.f / (1.f + du.w / sp);
    ushort4 o;
    o.x = f2bf(wv.x * a0); o.y = f2bf(wv.y * a1);
    o.z = f2bf(wv.z * a2); o.w = f2bf(wv.w * a3);
    *(ushort4*)&out[((size_t)bq * CC + n) * CC + cg] = o;
}

// ---------------- launch ----------------
extern "C" void kernel_launch(void* const* d_in, const int* in_sizes, int n_in,
                              void* d_out, int out_size, void* d_ws, size_t ws_size,
                              hipStream_t stream) {
    const float* x      = (const float*)d_in[0];
    const float* W_attn = (const float*)d_in[1];
    const float* b_attn = (const float*)d_in[2];
    const float* W_proj = (const float*)d_in[3];
    const float* b_proj = (const float*)d_in[4];
    const float* temp   = (const float*)d_in[5];

    // xb (x as bf16, 32MB) lives in the FIRST HALF of d_out: fully dead before
    // GEMM2 overwrites d_out with the fp32 result.
    unsigned short* xb = (unsigned short*)d_out;

    char* ws = (char*)d_ws;
    unsigned short* w16   = (unsigned short*)(ws);             // 33554432 B (w, then y in-place)
    unsigned short* Wa16  = (unsigned short*)(ws + 33554432);  // 2097152 B
    unsigned short* Wp16b = (unsigned short*)(ws + 35651584);  // 8388608 B (per-batch Wp')
    float* S     = (float*)(ws + 44040192);  // 16384 B
    float* dotsU = (float*)(ws + 44056576);  // 16384 B
    float* sumPi = (float*)(ws + 44072960);  // 256 B

    // conversions
    k_f32_to_bf16<<<dim3(16384), dim3(256), 0, stream>>>(x, xb, 4194304);
    k_f32_to_bf16<<<dim3(1024), dim3(256), 0, stream>>>(W_attn, Wa16, 262144);

    // zero accumulators (S, dotsU, sumPi contiguous)
    hipMemsetAsync(S, 0, 16384 + 16384 + 256, stream);

    // GEMM1: w16 = bf16(xb @ Wa^T + b_attn); fused S[b,c] = sum_t w^2
    k_gemm256<0><<<dim3(256), dim3(512), 0, stream>>>(
        xb, Wa16, b_attn, w16, S, BB * TT, CC, CC);

    // head-softmax per token; in-place w16 <- bf16(-(w*Pi)); dotsU, sumPi
    k_row_softmax<<<dim3(512), dim3(256), 0, stream>>>(w16, S, temp, dotsU, sumPi);

    // per-batch projection weights with attn fold: Wp'[b] = attn ⊙ Wp
    k_scale_wproj<<<dim3(4096), dim3(256), 0, stream>>>(W_proj, dotsU, sumPi, Wp16b);

    // GEMM2: out = y @ Wp'[b]^T + b_proj (fp32, overwrites xb region of d_out)
    k_gemm256<1><<<dim3(256), dim3(512), 0, stream>>>(
        w16, Wp16b, b_proj, d_out, nullptr, BB * TT, CC, CC);
}

// Round 11
// 129.725 us; speedup vs baseline: 1.5251x; 1.0099x over previous
//
#include <hip/hip_runtime.h>
#include <hip/hip_bf16.h>

// Problem constants: B=4, T=4096, C=1024, H=16, D=64
#define BB 4
#define TT 4096
#define CC 1024
#define HH 16
#define DD 64

typedef __attribute__((ext_vector_type(8))) short short8;
typedef __attribute__((ext_vector_type(8))) __bf16 bf16x8;
typedef __attribute__((ext_vector_type(4))) float f32x4;

static __device__ __forceinline__ unsigned short f2bf(float f) {
    unsigned int u = __builtin_bit_cast(unsigned int, f);
    unsigned int r = (u + 0x7FFFu + ((u >> 16) & 1u)) >> 16;
    return (unsigned short)r;
}
static __device__ __forceinline__ float bf2f(unsigned short h) {
    return __builtin_bit_cast(float, ((unsigned int)h) << 16);
}
static __device__ __forceinline__ short8 pack8s(f32x4 a, f32x4 b) {
    short8 r;
    r[0]=(short)f2bf(a[0]); r[1]=(short)f2bf(a[1]); r[2]=(short)f2bf(a[2]); r[3]=(short)f2bf(a[3]);
    r[4]=(short)f2bf(b[0]); r[5]=(short)f2bf(b[1]); r[6]=(short)f2bf(b[2]); r[7]=(short)f2bf(b[3]);
    return r;
}

// ---------------- fp32 -> bf16 conversion (weights only) ----------------
__global__ void k_f32_to_bf16(const float* __restrict__ src,
                              unsigned short* __restrict__ dst, int n4) {
    int i = blockIdx.x * 256 + threadIdx.x;
    if (i >= n4) return;
    float4 v = ((const float4*)src)[i];
    ushort4 o;
    o.x = f2bf(v.x); o.y = f2bf(v.y); o.z = f2bf(v.z); o.w = f2bf(v.w);
    ((ushort4*)dst)[i] = o;
}

// ================= 256x256 phase-pipelined bf16 GEMM =================
// C[m,n] = sum_k A[m,k]*B[n,k] + bias[n];  B: NxK row-major bf16.
// 8 waves (2M x 4N), per-wave output 128x64. BK=32.
// 4-buffer LDS rotation; 2 phases/K-tile; counted vmcnt, never 0 in-loop.
// B fragments read once per K-tile, reused in registers for phase 1.
// MODE 0: A = fp32 (x) REG-STAGED: plain loads (tile kt+4 issued at kt) ->
//         f2bf pack -> ds_write_b128 into the same swizzled bf16 layout at
//         kt+1 (dest buf's readers finished at kt -> race-free). Compiler's
//         auto vmcnt before the reg use acts as the counted wait (=6).
//         C written bf16 + fused column sum-of-squares S.
// MODE 1: A = bf16 via global_load_lds (stage kt+3 at kt); C fp32;
//         B is PER-BATCH (Wp' holds attnScale fold): Bbase += b*N*K.
#define GBM 256
#define GBN 256
#define GBK 32

static __device__ __forceinline__ void stage_tile32(
    const unsigned short* __restrict__ Gbase, unsigned short* lbase,
    int k0, int K, int wave, int lane)
{
    #pragma unroll
    for (int q = 0; q < 2; ++q) {
        int c = (wave * 2 + q) * 64 + lane;
        int r = c >> 2;
        int j = c & 3;
        int srcj = (j - (r >> 1)) & 3;
        const unsigned short* g = Gbase + (size_t)r * K + k0 + srcj * 8;
        __builtin_amdgcn_global_load_lds(
            (const __attribute__((address_space(1))) void*)g,
            (__attribute__((address_space(3))) void*)(lbase + (wave * 2 + q) * 512),
            16, 0, 0);
    }
}

// A reg-set: 2 chunks x 8 floats
struct ARegs { f32x4 v0, v1, v2, v3; };

#define LOAD_A(S, k4_) do { \
    const float* _p0 = aG0 + (size_t)(k4_) * GBK; \
    const float* _p1 = aG1 + (size_t)(k4_) * GBK; \
    (S).v0 = *(const f32x4*)_p0; (S).v1 = *(const f32x4*)(_p0 + 4); \
    (S).v2 = *(const f32x4*)_p1; (S).v3 = *(const f32x4*)(_p1 + 4); \
} while(0)

#define WRITE_A(S, dstbuf) do { \
    *(short8*)&(dstbuf)[c0 * 8] = pack8s((S).v0, (S).v1); \
    *(short8*)&(dstbuf)[c1 * 8] = pack8s((S).v2, (S).v3); \
} while(0)

// one K-tile: WS = reg set holding A(kt+3) (written now), LS = set to fill with A(kt+4)
#define K_TILE(kt_, WS, LS) do { \
    const int _kt = (kt_); \
    const unsigned short* buf = lds[_kt & 3]; \
    unsigned short* sbuf = lds[(_kt + 3) & 3]; \
    int _k3 = _kt + 3; if (_k3 >= nt) _k3 = nt - 1; \
    int _k4 = _kt + 4; if (_k4 >= nt) _k4 = nt - 1; \
    /* ---- phase 0: mi 0..3 ---- */ \
    short8 af0[4], bf0[4]; \
    _Pragma("unroll") for (int i = 0; i < 4; ++i) af0[i] = *(const short8*)&buf[aoff + i * 512]; \
    _Pragma("unroll") for (int i = 0; i < 4; ++i) bf0[i] = *(const short8*)&buf[boff + i * 512]; \
    if (MODE == 0) { LOAD_A(LS, _k4); WRITE_A(WS, sbuf); } \
    else           { stage_tile32(Ab16, sbuf, _k3 * GBK, K, wave, lane); } \
    __builtin_amdgcn_s_barrier(); \
    asm volatile("s_waitcnt lgkmcnt(0)" ::: "memory"); \
    __builtin_amdgcn_s_setprio(1); \
    _Pragma("unroll") for (int mi = 0; mi < 4; ++mi) \
        _Pragma("unroll") for (int ni = 0; ni < 4; ++ni) \
            acc[mi][ni] = __builtin_amdgcn_mfma_f32_16x16x32_bf16( \
                __builtin_bit_cast(bf16x8, af0[mi]), \
                __builtin_bit_cast(bf16x8, bf0[ni]), acc[mi][ni], 0, 0, 0); \
    __builtin_amdgcn_s_setprio(0); \
    __builtin_amdgcn_s_barrier(); \
    /* ---- phase 1: mi 4..7 (B frags reused) ---- */ \
    short8 af1[4]; \
    _Pragma("unroll") for (int i = 0; i < 4; ++i) af1[i] = *(const short8*)&buf[aoff + (4 + i) * 512]; \
    stage_tile32(Bbase, sbuf + 8192, _k3 * GBK, K, wave, lane); \
    asm volatile("s_waitcnt vmcnt(8)" ::: "memory"); \
    __builtin_amdgcn_s_barrier(); \
    asm volatile("s_waitcnt lgkmcnt(0)" ::: "memory"); \
    __builtin_amdgcn_s_setprio(1); \
    _Pragma("unroll") for (int mi = 0; mi < 4; ++mi) \
        _Pragma("unroll") for (int ni = 0; ni < 4; ++ni) \
            acc[4 + mi][ni] = __builtin_amdgcn_mfma_f32_16x16x32_bf16( \
                __builtin_bit_cast(bf16x8, af1[mi]), \
                __builtin_bit_cast(bf16x8, bf0[ni]), acc[4 + mi][ni], 0, 0, 0); \
    __builtin_amdgcn_s_setprio(0); \
    __builtin_amdgcn_s_barrier(); \
} while(0)

template<int MODE>
__global__ __launch_bounds__(512, 2)
void k_gemm256(const void* __restrict__ Asrc,
               const unsigned short* __restrict__ B,
               const float* __restrict__ bias,
               void* __restrict__ Cout,
               float* __restrict__ S,
               int M, int N, int K)
{
    __shared__ unsigned short lds[4][16384];   // 128 KB (A 16KB + B 16KB per buf)
    const int tid  = threadIdx.x;
    const int wave = tid >> 6;
    const int lane = tid & 63;
    const int wr = wave >> 2;   // 0..1
    const int wc = wave & 3;    // 0..3
    const int fr = lane & 15;
    const int hi = lane >> 4;   // 0..3

    // XCD-aware bijective swizzle (256 blocks, 8 XCDs, chunk=32, bn fastest)
    const int wg  = blockIdx.x;
    const int swz = (wg & 7) * 32 + (wg >> 3);
    const int bn  = swz & 3;
    const int bm  = swz >> 2;
    const int b   = bm >> 4;    // batch (16 bm-tiles per batch)

    const float* Af32 = (const float*)Asrc + (size_t)(bm * GBM) * K;
    const unsigned short* Ab16 = (const unsigned short*)Asrc + (size_t)(bm * GBM) * K;
    const unsigned short* Bbase = B +
        ((size_t)((MODE == 1 ? b * N : 0) + bn * GBN)) * K;

    const int nt = K / GBK;   // 32

    // A reg-stage addressing: two 16B chunks per thread (c in 0..1023)
    const int c0 = (wave * 2) * 64 + lane;
    const int c1 = c0 + 64;
    const int r0 = c0 >> 2, s0 = ((c0 & 3) - (r0 >> 1)) & 3;
    const int r1 = c1 >> 2, s1 = ((c1 & 3) - (r1 >> 1)) & 3;
    const float* aG0 = Af32 + (size_t)r0 * K + s0 * 8;
    const float* aG1 = Af32 + (size_t)r1 * K + s1 * 8;

    // fragment read offsets (rotate swizzle slot)
    const int sl   = (hi + (fr >> 1)) & 3;
    const int aoff = (wr * 128 + fr) * 32 + sl * 8;          // + mi*512
    const int boff = 8192 + (wc * 64 + fr) * 32 + sl * 8;    // + ni*512

    f32x4 acc[8][4] = {};
    ARegs eS, oS;

    // ---- prologue ----
    if (MODE == 0) {
        ARegs t0, t1, t2;
        LOAD_A(t0, 0); LOAD_A(t1, 1); LOAD_A(t2, 2);          // 12 VMEM
        stage_tile32(Bbase, lds[0] + 8192, 0,       K, wave, lane);
        stage_tile32(Bbase, lds[1] + 8192, GBK,     K, wave, lane);
        stage_tile32(Bbase, lds[2] + 8192, 2 * GBK, K, wave, lane);
        WRITE_A(t0, lds[0]); WRITE_A(t1, lds[1]); WRITE_A(t2, lds[2]);
        LOAD_A(eS, 3);                                        // W(kt=0) holds A(3)
        asm volatile("s_waitcnt lgkmcnt(0)" ::: "memory");    // A writes done
        asm volatile("s_waitcnt vmcnt(8)" ::: "memory");      // B0 landed (B1,B2,eS in flight)
        __builtin_amdgcn_s_barrier();
    } else {
        stage_tile32(Ab16, lds[0],         0,       K, wave, lane);
        stage_tile32(Bbase, lds[0] + 8192, 0,       K, wave, lane);
        stage_tile32(Ab16, lds[1],         GBK,     K, wave, lane);
        stage_tile32(Bbase, lds[1] + 8192, GBK,     K, wave, lane);
        stage_tile32(Ab16, lds[2],         2 * GBK, K, wave, lane);
        stage_tile32(Bbase, lds[2] + 8192, 2 * GBK, K, wave, lane);
        asm volatile("s_waitcnt vmcnt(8)" ::: "memory");      // tile 0 landed
        __builtin_amdgcn_s_barrier();
    }

    // ---- main loop: 2 tiles per iteration, static register sets ----
    for (int ktp = 0; ktp < nt; ktp += 2) {
        K_TILE(ktp,     eS, oS);
        K_TILE(ktp + 1, oS, eS);
    }

    __syncthreads();   // full drain (vmcnt+lgkmcnt) before LDS reuse

    // ---- epilogue: C/D layout col=lane&15, row=(lane>>4)*4+j ----
    const int cg = fr;
    const int rg = hi * 4;
    float* sblk = (float*)&lds[0][0];
    if (MODE == 0) {
        if (tid < GBN) sblk[tid] = 0.f;
        __syncthreads();
    }
    float csum[4] = {};
    #pragma unroll
    for (int mi = 0; mi < 8; ++mi) {
        #pragma unroll
        for (int ni = 0; ni < 4; ++ni) {
            int col = bn * GBN + wc * 64 + ni * 16 + cg;
            float bv = bias[col];
            #pragma unroll
            for (int j = 0; j < 4; ++j) {
                int row = bm * GBM + wr * 128 + mi * 16 + rg + j;
                float v = acc[mi][ni][j] + bv;
                if (MODE == 0) {
                    ((unsigned short*)Cout)[(size_t)row * N + col] = f2bf(v);
                    csum[ni] += v * v;
                } else {
                    ((float*)Cout)[(size_t)row * N + col] = v;
                }
            }
        }
    }
    if (MODE == 0) {
        #pragma unroll
        for (int ni = 0; ni < 4; ++ni)
            atomicAdd(&sblk[wc * 64 + ni * 16 + cg], csum[ni]);
        __syncthreads();
        if (tid < GBN) atomicAdd(&S[b * CC + bn * GBN + tid], sblk[tid]);
    }
}

// ------- per-row softmax over heads + IN-PLACE y = bf16(-(w*Pi)) -------
__global__ __launch_bounds__(256)
void k_row_softmax(unsigned short* __restrict__ w16, const float* __restrict__ S,
                   const float* __restrict__ temp,
                   float* __restrict__ dotsU, float* __restrict__ sumPi)
{
    __shared__ float dots_local[CC];
    __shared__ float sPi_local[HH];
    const int tid  = threadIdx.x;
    const int wave = tid >> 6;
    const int lane = tid & 63;
    const int bb   = blockIdx.x >> 7;
    const int tile = blockIdx.x & 127;

    for (int c = tid; c < CC; c += 256) dots_local[c] = 0.f;
    if (tid < HH) sPi_local[tid] = 0.f;
    __syncthreads();

    const int g3 = lane >> 3;
    const int li = lane & 7;

    float inv[2][8], tsc[2];
    #pragma unroll
    for (int q = 0; q < 2; ++q) {
        int c = q * 512 + lane * 8;
        const float4* sp = (const float4*)&S[bb * CC + c];
        float4 s0 = sp[0], s1 = sp[1];
        inv[q][0] = 1.f / fmaxf(s0.x, 1e-24f); inv[q][1] = 1.f / fmaxf(s0.y, 1e-24f);
        inv[q][2] = 1.f / fmaxf(s0.z, 1e-24f); inv[q][3] = 1.f / fmaxf(s0.w, 1e-24f);
        inv[q][4] = 1.f / fmaxf(s1.x, 1e-24f); inv[q][5] = 1.f / fmaxf(s1.y, 1e-24f);
        inv[q][6] = 1.f / fmaxf(s1.z, 1e-24f); inv[q][7] = 1.f / fmaxf(s1.w, 1e-24f);
        tsc[q] = temp[q * 8 + g3];
    }

    float dacc[2][8] = {};
    float sPiAcc[2] = {};

    for (int i = 0; i < 8; ++i) {
        int t = tile * 32 + wave * 8 + i;
        unsigned short* row = w16 + ((size_t)bb * TT + t) * CC;
        float wf[2][8];
        float pq[2];
        #pragma unroll
        for (int q = 0; q < 2; ++q) {
            short8 v = *(const short8*)&row[q * 512 + lane * 8];
            float s = 0.f;
            #pragma unroll
            for (int j = 0; j < 8; ++j) {
                wf[q][j] = bf2f((unsigned short)v[j]);
                s += wf[q][j] * wf[q][j] * inv[q][j];
            }
            pq[q] = s;
        }
        #pragma unroll
        for (int off = 1; off < 8; off <<= 1) {
            pq[0] += __shfl_xor(pq[0], off);
            pq[1] += __shfl_xor(pq[1], off);
        }
        pq[0] *= tsc[0]; pq[1] *= tsc[1];
        float mx = fmaxf(pq[0], pq[1]);
        mx = fmaxf(mx, __shfl_xor(mx, 8));
        mx = fmaxf(mx, __shfl_xor(mx, 16));
        mx = fmaxf(mx, __shfl_xor(mx, 32));
        float e0 = __expf(pq[0] - mx), e1 = __expf(pq[1] - mx);
        float ss = e0 + e1;
        ss += __shfl_xor(ss, 8);
        ss += __shfl_xor(ss, 16);
        ss += __shfl_xor(ss, 32);
        float rs = 1.f / ss;
        float piv[2] = { e0 * rs, e1 * rs };
        #pragma unroll
        for (int q = 0; q < 2; ++q) {
            short8 yo;
            #pragma unroll
            for (int j = 0; j < 8; ++j) {
                dacc[q][j] += piv[q] * wf[q][j] * wf[q][j];
                yo[j] = (short)f2bf(-wf[q][j] * piv[q]);
            }
            *(short8*)&row[q * 512 + lane * 8] = yo;   // in-place y = -(w*Pi)
            if (li == 0) sPiAcc[q] += piv[q];
        }
    }

    #pragma unroll
    for (int q = 0; q < 2; ++q) {
        int c = q * 512 + lane * 8;
        #pragma unroll
        for (int j = 0; j < 8; ++j)
            atomicAdd(&dots_local[c + j], dacc[q][j]);
        if (li == 0) atomicAdd(&sPi_local[q * 8 + g3], sPiAcc[q]);
    }
    __syncthreads();
    for (int c = tid; c < CC; c += 256) atomicAdd(&dotsU[bb * CC + c], dots_local[c]);
    if (tid < HH) atomicAdd(&sumPi[bb * HH + tid], sPi_local[tid]);
}

// -- Wp'[b,n,c] = bf16( Wp[n,c] * (+1/(1 + dotsU[b,c]/(sumPi[b,h]+1e-8))) ) --
// (sign: y already carries the minus)
__global__ void k_scale_wproj(const float* __restrict__ Wp,
                              const float* __restrict__ dotsU,
                              const float* __restrict__ sumPi,
                              unsigned short* __restrict__ out)
{
    int i = blockIdx.x * 256 + threadIdx.x;   // 1,048,576 groups of 4
    int bq  = i >> 18;                        // batch
    int rem = i & 262143;
    int n   = rem >> 8;
    int cg  = (rem & 255) * 4;
    float4 wv = *(const float4*)&Wp[n * CC + cg];
    float4 du = *(const float4*)&dotsU[bq * CC + cg];
    float sp = sumPi[bq * HH + (cg >> 6)] + 1e-8f;
    float a0 = 1.f / (1.f + du.x / sp);
    float a1 = 1.f / (1.f + du.y / sp);
    float a2 = 1.f / (1.f + du.z / sp);
    float a3 = 1.f / (1.f + du.w / sp);
    ushort4 o;
    o.x = f2bf(wv.x * a0); o.y = f2bf(wv.y * a1);
    o.z = f2bf(wv.z * a2); o.w = f2bf(wv.w * a3);
    *(ushort4*)&out[((size_t)bq * CC + n) * CC + cg] = o;
}

// ---------------- launch ----------------
extern "C" void kernel_launch(void* const* d_in, const int* in_sizes, int n_in,
                              void* d_out, int out_size, void* d_ws, size_t ws_size,
                              hipStream_t stream) {
    const float* x      = (const float*)d_in[0];
    const float* W_attn = (const float*)d_in[1];
    const float* b_attn = (const float*)d_in[2];
    const float* W_proj = (const float*)d_in[3];
    const float* b_proj = (const float*)d_in[4];
    const float* temp   = (const float*)d_in[5];

    char* ws = (char*)d_ws;
    unsigned short* w16   = (unsigned short*)(ws);             // 33554432 B (w, then y in-place)
    unsigned short* Wa16  = (unsigned short*)(ws + 33554432);  // 2097152 B
    unsigned short* Wp16b = (unsigned short*)(ws + 35651584);  // 8388608 B (per-batch Wp')
    float* S     = (float*)(ws + 44040192);  // 16384 B
    float* dotsU = (float*)(ws + 44056576);  // 16384 B
    float* sumPi = (float*)(ws + 44072960);  // 256 B

    // W_attn -> bf16 (x is consumed as fp32 directly by GEMM1's reg-staged A path)
    k_f32_to_bf16<<<dim3(1024), dim3(256), 0, stream>>>(W_attn, Wa16, 262144);

    // zero accumulators (S, dotsU, sumPi contiguous)
    hipMemsetAsync(S, 0, 16384 + 16384 + 256, stream);

    // GEMM1: w16 = bf16(x @ Wa^T + b_attn); fused S[b,c] = sum_t w^2
    k_gemm256<0><<<dim3(256), dim3(512), 0, stream>>>(
        x, Wa16, b_attn, w16, S, BB * TT, CC, CC);

    // head-softmax per token; in-place w16 <- bf16(-(w*Pi)); dotsU, sumPi
    k_row_softmax<<<dim3(512), dim3(256), 0, stream>>>(w16, S, temp, dotsU, sumPi);

    // per-batch projection weights with attn fold: Wp'[b] = attn ⊙ Wp
    k_scale_wproj<<<dim3(4096), dim3(256), 0, stream>>>(W_proj, dotsU, sumPi, Wp16b);

    // GEMM2: out = y @ Wp'[b]^T + b_proj
    k_gemm256<1><<<dim3(256), dim3(512), 0, stream>>>(
        w16, Wp16b, b_proj, d_out, nullptr, BB * TT, CC, CC);
}